// Round 12
// baseline (1299.796 us; speedup 1.0000x reference)
//
#include <hip/hip_runtime.h>
#include <math.h>

// ---------------------------------------------------------------------------
// MultiReferenceWindowAttention — bf16-MFMA GEMMs + attention.
// B_=128, T=4, M=4, N=64, C=192, nH=6, hd=32, BT=512
// Workspace (<= proven 177,340,416 B):
//   qbuf f32  @ 0      (24 MB)  q -> later qq
//   xp  bf16  @ 24 MB  (48 MB)
//   kbuf bf16 @ 72 MB  (12 MB)  k -> later kk-chunk(bf16) -> later opo
//   vbuf bf16 @ 84 MB  (12 MB)  v
//   kk bf16 @ 72 MB (31.5 MB/chunk), vv bf16 @ 102 MB (31.5 MB/chunk)
// d_out doubles as opool scratch (fully rewritten by final GEMM).
//
// VGPR/SPILL MODEL (r7..r11): hipcc targets ~84 VGPR for 768-thread blocks
// (6 waves/SIMD) regardless of launch_bounds min-waves or LDS size (r11:
// 86 KB pad still gave 84). The kernel must keep LIVE STATE <= ~84: r7 fit
// (phases: qreg+s | s+o, each ~80); r9's bulk kk[4] arrays and r11's mrow[4]
// mask preload each added +16 live across QK -> spill (1.7-2.9 GB scratch).
// Rule: stream unpack temps one u32x4 at a time; no cross-phase preloads.
// ---------------------------------------------------------------------------

typedef float f32x4 __attribute__((ext_vector_type(4)));
typedef short s16x8 __attribute__((ext_vector_type(8)));
typedef unsigned short u16x4 __attribute__((ext_vector_type(4)));
typedef unsigned short u16x8 __attribute__((ext_vector_type(8)));
typedef unsigned u32x4 __attribute__((ext_vector_type(4)));

__device__ __forceinline__ unsigned short f2bf(float f) {
    union { float f; unsigned u; } c; c.f = f;
    return (unsigned short)((c.u + 0x7fffu + ((c.u >> 16) & 1u)) >> 16);
}
__device__ __forceinline__ float bf2f(unsigned short h) {
    union { unsigned u; float f; } c; c.u = ((unsigned)h) << 16;
    return c.f;
}
__device__ __forceinline__ float bflo(unsigned w) {   // low bf16 of packed u32
    union { unsigned u; float f; } c; c.u = w << 16;
    return c.f;
}
__device__ __forceinline__ float bfhi(unsigned w) {   // high bf16 of packed u32
    union { unsigned u; float f; } c; c.u = w & 0xffff0000u;
    return c.f;
}

// ---------------------------------------------------------------------------
// MFMA bf16 GEMM:  C[row, oc] = sum_k Arow[k] * W[oc][k] + bias[oc]
// Block tile 128 rows x 96 oc, K=192 staged in 2 halves of 96.
// SRC: 0 = A plain f32 rows; 1 = mean_m xp(bf16) + pos; 2 = seq rows from xp.
// EPI: 0 plain, 1 exact gelu, 2 split oc@192 -> C0/C1 (b0 len 384),
//      3 split oc@192 -> C0 (W0,b0) / C1 (W1,b1)
// OUTBF: 0 = f32 out, 1 = bf16 out.
// ---------------------------------------------------------------------------
template <int SRC, int EPI, int OUTBF>
__global__ __launch_bounds__(256, 3)
void mgemm_kernel(const float* __restrict__ A, const unsigned short* __restrict__ Axp,
                  const float* __restrict__ pos,
                  const float* __restrict__ W0, const float* __restrict__ W1,
                  const float* __restrict__ b0, const float* __restrict__ b1,
                  void* __restrict__ C0v, void* __restrict__ C1v, int c0)
{
    __shared__ __align__(16) char As[128 * 192];   // 24 KB bf16 [row][k(96)]
    __shared__ __align__(16) char Bs[96 * 192];    // 18 KB bf16 [oc][k(96)]
    const int tid = threadIdx.x;
    const int gm0 = blockIdx.x * 128;
    const int gn0 = blockIdx.y * 96;
    const int wid = tid >> 6;
    const int wm = wid >> 1, wn = wid & 1;
    const int lane = tid & 63;
    const int lr = lane & 15;
    const int lk = lane >> 4;

    const bool hiN = (gn0 >= 192);
    const float* Wsel = (EPI == 3 && hiN) ? W1 : W0;
    const int wrow0 = (EPI == 3 && hiN) ? (gn0 - 192) : gn0;

    f32x4 acc[4][3];
#pragma unroll
    for (int i = 0; i < 4; i++)
#pragma unroll
        for (int j = 0; j < 3; j++) acc[i][j] = (f32x4){0.f, 0.f, 0.f, 0.f};

    for (int kb = 0; kb < 192; kb += 96) {
#pragma unroll
        for (int it = 0; it < 12; it++) {
            int f4 = tid + it * 256;
            int row = f4 / 24;
            int kc4 = (f4 - row * 24) * 4;
            float av[4];
            if (SRC == 0) {
                float4 v = *reinterpret_cast<const float4*>(
                    &A[(size_t)(gm0 + row) * 192 + kb + kc4]);
                av[0] = v.x; av[1] = v.y; av[2] = v.z; av[3] = v.w;
            } else {
                int g = gm0 + row;
                int bt, tok;
                if (SRC == 1) { bt = g >> 6; tok = g & 63; }
                else { bt = g / 320; tok = g - bt * 320; bt += c0; }
                int n = tok & 63;
                int kcol = kb + kc4;
                float4 p4 = *reinterpret_cast<const float4*>(&pos[n * 192 + kcol]);
                float pv[4] = {p4.x, p4.y, p4.z, p4.w};
                if (SRC == 2 && tok >= 64) {
                    int mm = (tok >> 6) - 1;
                    u16x4 a = *reinterpret_cast<const u16x4*>(
                        &Axp[(size_t)bt * 49152 + mm * 12288 + n * 192 + kcol]);
#pragma unroll
                    for (int jj = 0; jj < 4; jj++) av[jj] = bf2f(a[jj]) + pv[jj];
                } else {
                    size_t xb = (size_t)bt * 49152 + n * 192 + kcol;
                    u16x4 a0 = *reinterpret_cast<const u16x4*>(&Axp[xb]);
                    u16x4 a1 = *reinterpret_cast<const u16x4*>(&Axp[xb + 12288]);
                    u16x4 a2 = *reinterpret_cast<const u16x4*>(&Axp[xb + 24576]);
                    u16x4 a3 = *reinterpret_cast<const u16x4*>(&Axp[xb + 36864]);
#pragma unroll
                    for (int jj = 0; jj < 4; jj++)
                        av[jj] = 0.25f * (bf2f(a0[jj]) + bf2f(a1[jj]) +
                                          bf2f(a2[jj]) + bf2f(a3[jj])) + pv[jj];
                }
            }
            u16x4 bvv;
#pragma unroll
            for (int jj = 0; jj < 4; jj++) bvv[jj] = f2bf(av[jj]);
            int boff = (kc4 * 2) ^ ((row & 3) << 4);
            *reinterpret_cast<u16x4*>(As + row * 192 + boff) = bvv;
        }
#pragma unroll
        for (int it = 0; it < 9; it++) {
            int f4 = tid + it * 256;
            int row = f4 / 24;
            int kc4 = (f4 - row * 24) * 4;
            float4 v = *reinterpret_cast<const float4*>(
                &Wsel[(size_t)(wrow0 + row) * 192 + kb + kc4]);
            u16x4 bvv;
            bvv[0] = f2bf(v.x); bvv[1] = f2bf(v.y); bvv[2] = f2bf(v.z); bvv[3] = f2bf(v.w);
            int boff = (kc4 * 2) ^ ((row & 3) << 4);
            *reinterpret_cast<u16x4*>(Bs + row * 192 + boff) = bvv;
        }
        __syncthreads();

#pragma unroll
        for (int ks = 0; ks < 3; ks++) {
            s16x8 af[4], bf[3];
#pragma unroll
            for (int i = 0; i < 4; i++) {
                int row = wm * 64 + i * 16 + lr;
                int off = (ks * 64 + lk * 16) ^ ((row & 3) << 4);
                af[i] = *reinterpret_cast<const s16x8*>(As + row * 192 + off);
            }
#pragma unroll
            for (int j = 0; j < 3; j++) {
                int row = wn * 48 + j * 16 + lr;
                int off = (ks * 64 + lk * 16) ^ ((row & 3) << 4);
                bf[j] = *reinterpret_cast<const s16x8*>(Bs + row * 192 + off);
            }
#pragma unroll
            for (int i = 0; i < 4; i++)
#pragma unroll
                for (int j = 0; j < 3; j++)
                    acc[i][j] = __builtin_amdgcn_mfma_f32_16x16x32_bf16(
                        af[i], bf[j], acc[i][j], 0, 0, 0);
        }
        __syncthreads();
    }

#pragma unroll
    for (int j = 0; j < 3; j++) {
        int bcol = gn0 + wn * 48 + j * 16 + lr;
        float bv = (EPI == 3 && bcol >= 192) ? b1[bcol - 192] : b0[bcol];
        void* dst = C0v;
        int oc = bcol;
        if ((EPI == 2 || EPI == 3) && bcol >= 192) { dst = C1v; oc = bcol - 192; }
#pragma unroll
        for (int i = 0; i < 4; i++) {
            int rbase = gm0 + wm * 64 + i * 16 + lk * 4;
#pragma unroll
            for (int r = 0; r < 4; r++) {
                float v = acc[i][j][r] + bv;
                if (EPI == 1) v = 0.5f * v * (1.f + erff(v * 0.70710678118654752440f));
                size_t idx = (size_t)(rbase + r) * 192 + oc;
                if (OUTBF) ((unsigned short*)dst)[idx] = f2bf(v);
                else       ((float*)dst)[idx] = v;
            }
        }
    }
}

// ---------------------------------------------------------------------------
// Fused window attention, key-split, bf16 LDS: block = (bb,t,m), 768 thr = 12
// waves. Wave w: head h = w>>1, keys [(w&1)*32 .. +32). K/V/mask/rpb stored
// bf16 in LDS (66.5 KB -> 2 blocks/CU if VGPR <= 84). Live-state discipline:
// stream one u32x4 unpack at a time; mask read per-key (scalar LDS), NO
// cross-phase preloads (see header VGPR model).
// smem (u16 idx): K @0 [64*192], V @12288, mask @24576 [64*66],
//                 rpbT @28800 [6*226], exm(f32) @30160, exl(f32) @31696.
// ---------------------------------------------------------------------------
__global__ __launch_bounds__(768, 1)
void winattn_kernel(const float* __restrict__ qbuf,
                    const unsigned short* __restrict__ kbuf,
                    const unsigned short* __restrict__ vbuf,
                    const float* __restrict__ mask,
                    const float* __restrict__ rpbt, unsigned short* __restrict__ xp)
{
    __shared__ __align__(16) unsigned short smem[33232];   // 66464 B
    float* exm = (float*)(smem + 30160);
    float* exl = (float*)(smem + 31696);
    unsigned* obuf = (unsigned*)smem;                      // alias K/V after PV
    const int tid = threadIdx.x;
    const int bid = blockIdx.x;            // bb*16 + t*4 + m
    const int bb = bid >> 4;
    const int t = (bid >> 2) & 3;
    const int m = bid & 3;
    const int w = tid >> 6;
    const int h = w >> 1;
    const int lane = tid & 63;

    const int kvbase = (bb * 4 + m) * 12288;
#pragma unroll
    for (int it = 0; it < 2; it++) {
        int i8 = tid + it * 768;           // 0..1535
        *reinterpret_cast<u16x8*>(&smem[i8 * 8]) =
            *reinterpret_cast<const u16x8*>(&kbuf[kvbase + i8 * 8]);
        *reinterpret_cast<u16x8*>(&smem[12288 + i8 * 8]) =
            *reinterpret_cast<const u16x8*>(&vbuf[kvbase + i8 * 8]);
    }
    const int widx = bb & 63;
    for (int f = tid; f < 2048; f += 768) {
        int q = f >> 5, ee = (f & 31) * 2;
        float2 mv = *reinterpret_cast<const float2*>(&mask[widx * 4096 + q * 64 + ee]);
        unsigned pk = (unsigned)f2bf(mv.x) | ((unsigned)f2bf(mv.y) << 16);
        *reinterpret_cast<unsigned*>(&smem[24576 + q * 66 + ee]) = pk;
    }
    for (int f = tid; f < 1350; f += 768) {
        int hh = f / 225, rr = f - hh * 225;
        smem[28800 + hh * 226 + rr] = f2bf(rpbt[rr * 6 + hh]);
    }

    float qreg[32];
    const int qbase = ((bb * 4 + t) * 64 + lane) * 192 + h * 32;
#pragma unroll
    for (int j = 0; j < 8; j++) {
        float4 v = *reinterpret_cast<const float4*>(&qbuf[qbase + j * 4]);
        qreg[4 * j] = v.x; qreg[4 * j + 1] = v.y;
        qreg[4 * j + 2] = v.z; qreg[4 * j + 3] = v.w;
    }
    __syncthreads();

    const float scale = 0.17677669529663688110f;  // 1/sqrt(32)
    const int ni = lane >> 3, nj = lane & 7;
    const int e0 = (w & 1) << 5;

    float s[32];
#pragma unroll
    for (int ee = 0; ee < 32; ee++) {
        int e = e0 + ee;
        const u32x4* kr = reinterpret_cast<const u32x4*>(&smem[e * 192 + h * 32]);
        float d0 = 0.f, d1 = 0.f;
#pragma unroll
        for (int v4 = 0; v4 < 4; v4++) {
            u32x4 kw = kr[v4];             // one u32x4 live at a time
#pragma unroll
            for (int jj = 0; jj < 4; jj++) {
                unsigned wv = kw[jj];
                int b = v4 * 8 + jj * 2;
                d0 += qreg[b] * bflo(wv);
                d1 += qreg[b + 1] * bfhi(wv);
            }
        }
        int ridx = (ni - (e >> 3) + 7) * 15 + (nj - (e & 7) + 7);
        s[ee] = (d0 + d1) * scale + bf2f(smem[28800 + h * 226 + ridx])
              + bf2f(smem[24576 + lane * 66 + e]);
    }
    float mrun = s[0];
#pragma unroll
    for (int ee = 1; ee < 32; ee++) mrun = fmaxf(mrun, s[ee]);
    float lrun = 0.f;
#pragma unroll
    for (int ee = 0; ee < 32; ee++) { s[ee] = __expf(s[ee] - mrun); lrun += s[ee]; }

    float o[32];
#pragma unroll
    for (int d = 0; d < 32; d++) o[d] = 0.f;
#pragma unroll
    for (int ee = 0; ee < 32; ee++) {
        float p = s[ee];
        const u32x4* vr = reinterpret_cast<const u32x4*>(&smem[12288 + (e0 + ee) * 192 + h * 32]);
#pragma unroll
        for (int v4 = 0; v4 < 4; v4++) {
            u32x4 vw = vr[v4];             // one u32x4 live at a time
#pragma unroll
            for (int jj = 0; jj < 4; jj++) {
                unsigned wv = vw[jj];
                int b = v4 * 8 + jj * 2;
                o[b] += p * bflo(wv);
                o[b + 1] += p * bfhi(wv);
            }
        }
    }

    // ---- pair merge: waves (2h, 2h+1); obuf aliases dead K/V region ----
    __syncthreads();
    exm[w * 64 + lane] = mrun;
    __syncthreads();
    float mo = exm[(w ^ 1) * 64 + lane];
    float mt = fmaxf(mrun, mo);
    float fs = __expf(mrun - mt);
    if (w & 1) {
        unsigned* ob = &obuf[h * 1088 + lane * 17];
#pragma unroll
        for (int j = 0; j < 16; j++) {
            unsigned lo = f2bf(fs * o[2 * j]);
            unsigned hi = f2bf(fs * o[2 * j + 1]);
            ob[j] = lo | (hi << 16);
        }
        exl[w * 64 + lane] = fs * lrun;
    }
    __syncthreads();
    if (!(w & 1)) {
        float lt = fs * lrun + exl[(w + 1) * 64 + lane];
        const float inv = 1.f / lt;
        const unsigned* ob = &obuf[h * 1088 + lane * 17];
        const int obase = bb * 196608 + m * 49152 + t * 12288 + h * 2048 + lane * 32;
#pragma unroll
        for (int j = 0; j < 8; j++) {
            unsigned p0 = ob[2 * j], p1 = ob[2 * j + 1];
            u16x4 v;
            v[0] = f2bf((fs * o[4 * j]     + bf2f((unsigned short)(p0 & 0xffff))) * inv);
            v[1] = f2bf((fs * o[4 * j + 1] + bf2f((unsigned short)(p0 >> 16))) * inv);
            v[2] = f2bf((fs * o[4 * j + 2] + bf2f((unsigned short)(p1 & 0xffff))) * inv);
            v[3] = f2bf((fs * o[4 * j + 3] + bf2f((unsigned short)(p1 >> 16))) * inv);
            *reinterpret_cast<u16x4*>(&xp[obase + j * 4]) = v;
        }
    }
}

// ---------------------------------------------------------------------------
// Pooling attention (r7 known-good f32-LDS version): block = (h, btl),
// 320 threads = 5 waves. Wave w handles key tiles {w, w+5} of 10 (32 keys)
// with private online softmax; partials merged via LDS.
// ---------------------------------------------------------------------------
__global__ __launch_bounds__(320)
void poolattn3_kernel(const unsigned short* __restrict__ kk,
                      const unsigned short* __restrict__ vv,
                      const float* __restrict__ qq, float* __restrict__ opool, int c0)
{
    __shared__ float ubuf[10560];      // union: K/V slots (w*2048) | sco (w*2112+q*33+d)
    __shared__ float scm[320], scl[320];
    const int tid = threadIdx.x;
    const int w = tid >> 6, lane = tid & 63;
    const int h = blockIdx.x, btl = blockIdx.y;
    const int bt = c0 + btl;
    float* Kf = ubuf + w * 2048;
    float* Vf = Kf + 1024;

    float qreg[32];
    const size_t qbase = (size_t)(bt * 64 + lane) * 192 + h * 32;
#pragma unroll
    for (int j = 0; j < 8; j++) {
        float4 v = *reinterpret_cast<const float4*>(&qq[qbase + j * 4]);
        qreg[4 * j] = v.x; qreg[4 * j + 1] = v.y;
        qreg[4 * j + 2] = v.z; qreg[4 * j + 3] = v.w;
    }
    const float scale = 0.17677669529663688110f;
    float mrun = -3.0e38f, lrun = 0.f;
    float o[32];
#pragma unroll
    for (int d = 0; d < 32; d++) o[d] = 0.f;

#pragma unroll
    for (int it = 0; it < 2; it++) {
        const int tt = w + it * 5;
        const unsigned short* ks = kk + (size_t)(btl * 320 + tt * 32) * 192 + h * 32;
        const unsigned short* vs = vv + (size_t)(btl * 320 + tt * 32) * 192 + h * 32;
#pragma unroll
        for (int ci = 0; ci < 2; ci++) {
            int idx = lane + ci * 64;          // 0..127
            int j = idx >> 2, q4 = (idx & 3) * 8;
            s16x8 kv8 = *reinterpret_cast<const s16x8*>(&ks[j * 192 + q4]);
            s16x8 vv8 = *reinterpret_cast<const s16x8*>(&vs[j * 192 + q4]);
            f32x4 lo, hi, vlo, vhi;
#pragma unroll
            for (int e = 0; e < 4; e++) {
                lo[e] = bf2f((unsigned short)kv8[e]);
                hi[e] = bf2f((unsigned short)kv8[e + 4]);
                vlo[e] = bf2f((unsigned short)vv8[e]);
                vhi[e] = bf2f((unsigned short)vv8[e + 4]);
            }
            *reinterpret_cast<f32x4*>(Kf + j * 32 + q4) = lo;
            *reinterpret_cast<f32x4*>(Kf + j * 32 + q4 + 4) = hi;
            *reinterpret_cast<f32x4*>(Vf + j * 32 + q4) = vlo;
            *reinterpret_cast<f32x4*>(Vf + j * 32 + q4 + 4) = vhi;
        }
        float s[32];
#pragma unroll
        for (int j = 0; j < 32; j++) {
            const float4* kr = reinterpret_cast<const float4*>(Kf + j * 32);
            float d0 = 0, d1 = 0, d2 = 0, d3 = 0;
#pragma unroll
            for (int q8 = 0; q8 < 8; q8++) {
                float4 k4 = kr[q8];
                d0 += qreg[q8 * 4] * k4.x;
                d1 += qreg[q8 * 4 + 1] * k4.y;
                d2 += qreg[q8 * 4 + 2] * k4.z;
                d3 += qreg[q8 * 4 + 3] * k4.w;
            }
            s[j] = (d0 + d1 + d2 + d3) * scale;
        }
        float mt = s[0];
#pragma unroll
        for (int j = 1; j < 32; j++) mt = fmaxf(mt, s[j]);
        float mnew = fmaxf(mrun, mt);
        float fct = __expf(mrun - mnew);
        lrun *= fct;
#pragma unroll
        for (int d = 0; d < 32; d++) o[d] *= fct;
#pragma unroll
        for (int j = 0; j < 32; j++) { float p = __expf(s[j] - mnew); lrun += p; s[j] = p; }
#pragma unroll
        for (int j = 0; j < 32; j++) {
            float p = s[j];
            const float4* vr = reinterpret_cast<const float4*>(Vf + j * 32);
#pragma unroll
            for (int d8 = 0; d8 < 8; d8++) {
                float4 v4 = vr[d8];
                o[d8 * 4] += p * v4.x; o[d8 * 4 + 1] += p * v4.y;
                o[d8 * 4 + 2] += p * v4.z; o[d8 * 4 + 3] += p * v4.w;
            }
        }
        mrun = mnew;
    }
    __syncthreads();                 // everyone done with K/V region
    scm[w * 64 + lane] = mrun;
    scl[w * 64 + lane] = lrun;
#pragma unroll
    for (int d = 0; d < 32; d++) ubuf[w * 2112 + lane * 33 + d] = o[d];
    __syncthreads();

    if (w == 0) {
        float m5 = scm[lane];
#pragma unroll
        for (int ww = 1; ww < 5; ww++) m5 = fmaxf(m5, scm[ww * 64 + lane]);
        float den = 0.f;
        float od[32];
#pragma unroll
        for (int d = 0; d < 32; d++) od[d] = 0.f;
#pragma unroll
        for (int ww = 0; ww < 5; ww++) {
            float f = __expf(scm[ww * 64 + lane] - m5);
            den += f * scl[ww * 64 + lane];
            const float* src = ubuf + ww * 2112 + lane * 33;
#pragma unroll
            for (int d = 0; d < 32; d++) od[d] += f * src[d];
        }
        const float inv = 1.f / den;
        const size_t ob = (size_t)(bt * 64 + lane) * 192 + h * 32;
#pragma unroll
        for (int j = 0; j < 8; j++) {
            float4 v;
            v.x = od[4 * j] * inv; v.y = od[4 * j + 1] * inv;
            v.z = od[4 * j + 2] * inv; v.w = od[4 * j + 3] * inv;
            *reinterpret_cast<float4*>(&opool[ob + j * 4]) = v;
        }
    }
}

extern "C" void kernel_launch(void* const* d_in, const int* in_sizes, int n_in,
                              void* d_out, int out_size, void* d_ws, size_t ws_size,
                              hipStream_t stream) {
    (void)in_sizes; (void)n_in; (void)out_size; (void)ws_size;
    const float* x      = (const float*)d_in[0];
    const float* x_kv   = (const float*)d_in[1];
    const float* mask   = (const float*)d_in[2];
    const float* rpbt   = (const float*)d_in[3];
    const float* q_w    = (const float*)d_in[4];
    const float* q_b    = (const float*)d_in[5];
    const float* kv_w   = (const float*)d_in[6];
    const float* kv_b   = (const float*)d_in[7];
    const float* pos    = (const float*)d_in[8];
    const float* pq_w   = (const float*)d_in[9];
    const float* pq_b   = (const float*)d_in[10];
    const float* pk_w   = (const float*)d_in[11];
    const float* pk_b   = (const float*)d_in[12];
    const float* pv_w   = (const float*)d_in[13];
    const float* pv_b   = (const float*)d_in[14];
    const float* po_w   = (const float*)d_in[15];
    const float* po_b   = (const float*)d_in[16];
    const float* proj_w = (const float*)d_in[17];
    const float* proj_b = (const float*)d_in[18];
    float* out = (float*)d_out;
    char* ws = (char*)d_ws;

    float*          qbuf = (float*)(ws);                       // 24 MB
    unsigned short* xp   = (unsigned short*)(ws + 25165824u);  // 48 MB bf16
    unsigned short* kbuf = (unsigned short*)(ws + 75497472u);  // 12 MB bf16
    unsigned short* vbuf = (unsigned short*)(ws + 88080384u);  // 12 MB bf16
    float*          qq   = qbuf;
    unsigned short* kkc  = (unsigned short*)(ws + 75497472u);  // 31.5 MB / chunk
    unsigned short* vvc  = (unsigned short*)(ws + 106954752u); // 31.5 MB / chunk
    float*          opo  = (float*)(ws + 75497472u);           // after pooling
    float*          opool = out;                               // d_out as scratch

    dim3 blk(256);
    // q = x @ q_w^T + q_b
    mgemm_kernel<0, 0, 0><<<dim3(256, 2), blk, 0, stream>>>(
        x, nullptr, nullptr, q_w, nullptr, q_b, nullptr, qbuf, nullptr, 0);
    // k,v = x_kv @ kv_w^T + kv_b  (split at oc 192, bf16 out)
    mgemm_kernel<0, 2, 1><<<dim3(256, 4), blk, 0, stream>>>(
        x_kv, nullptr, nullptr, kv_w, nullptr, kv_b, nullptr, kbuf, vbuf, 0);
    winattn_kernel<<<2048, 768, 0, stream>>>(qbuf, kbuf, vbuf, mask, rpbt, xp);
    // qq = (mean_m xp + pos) @ pq_w^T + pq_b
    mgemm_kernel<1, 0, 0><<<dim3(256, 2), blk, 0, stream>>>(
        nullptr, xp, pos, pq_w, nullptr, pq_b, nullptr, qq, nullptr, 0);
    // pooling in 2 chunks of 256 bt
    for (int c0 = 0; c0 < 512; c0 += 256) {
        mgemm_kernel<2, 3, 1><<<dim3(640, 4), blk, 0, stream>>>(
            nullptr, xp, pos, pk_w, pv_w, pk_b, pv_b, kkc, vvc, c0);
        poolattn3_kernel<<<dim3(6, 256), 320, 0, stream>>>(kkc, vvc, qq, opool, c0);
    }
    // opo = gelu(opool @ po_w^T + po_b); out = opo @ proj_w^T + proj_b
    mgemm_kernel<0, 1, 0><<<dim3(256, 2), blk, 0, stream>>>(
        opool, nullptr, nullptr, po_w, nullptr, po_b, nullptr, opo, nullptr, 0);
    mgemm_kernel<0, 0, 0><<<dim3(256, 2), blk, 0, stream>>>(
        opo, nullptr, nullptr, proj_w, nullptr, proj_b, nullptr, out, nullptr, 0);
}

// Round 13
// 801.574 us; speedup vs baseline: 1.6216x; 1.6216x over previous
//
#include <hip/hip_runtime.h>
#include <math.h>

// ---------------------------------------------------------------------------
// MultiReferenceWindowAttention — bf16-MFMA GEMMs + attention.
// B_=128, T=4, M=4, N=64, C=192, nH=6, hd=32, BT=512
// Workspace (<= proven 177,340,416 B):
//   qbuf f32  @ 0      (24 MB)  q -> later qq
//   xp  bf16  @ 24 MB  (48 MB)
//   kbuf bf16 @ 72 MB  (12 MB)  k -> later kk-chunk(bf16) -> later opo
//   vbuf bf16 @ 84 MB  (12 MB)  v
//   kk bf16 @ 72 MB (31.5 MB/chunk), vv bf16 @ 102 MB (31.5 MB/chunk)
// d_out doubles as opool scratch (fully rewritten by final GEMM).
//
// VGPR/SPILL MODEL (r7..r12, final): for 768-thread blocks hipcc targets
// ~84 VGPR (2 blocks/CU) regardless of launch_bounds/LDS-padding, and will
// SPILL rather than exceed it. bf16-K/V-in-LDS variants need ~16 extra live
// regs (compiler hoists the 4 ds_read_b128 unpack loads; source-level
// "streaming" does not prevent this) -> 1.7-2.9 GB scratch, 3.4x slower.
// The f32-LDS compute core (r7) fits at VGPR 80 with zero spill. KEEP IT.
// K/V rows are read wave-uniform (broadcast, conflict-free), so the f32
// core is a balanced VALU/DS kernel (~38% VALUBusy) at 191 us.
// ---------------------------------------------------------------------------

typedef float f32x4 __attribute__((ext_vector_type(4)));
typedef short s16x8 __attribute__((ext_vector_type(8)));
typedef unsigned short u16x4 __attribute__((ext_vector_type(4)));
typedef unsigned short u16x8 __attribute__((ext_vector_type(8)));

__device__ __forceinline__ unsigned short f2bf(float f) {
    union { float f; unsigned u; } c; c.f = f;
    return (unsigned short)((c.u + 0x7fffu + ((c.u >> 16) & 1u)) >> 16);
}
__device__ __forceinline__ float bf2f(unsigned short h) {
    union { unsigned u; float f; } c; c.u = ((unsigned)h) << 16;
    return c.f;
}

// ---------------------------------------------------------------------------
// MFMA bf16 GEMM:  C[row, oc] = sum_k Arow[k] * W[oc][k] + bias[oc]
// Block tile 128 rows x 96 oc, K=192 staged in 2 halves of 96.
// SRC: 0 = A plain f32 rows; 1 = mean_m xp(bf16) + pos; 2 = seq rows from xp.
// EPI: 0 plain, 1 exact gelu, 2 split oc@192 -> C0/C1 (b0 len 384),
//      3 split oc@192 -> C0 (W0,b0) / C1 (W1,b1)
// OUTBF: 0 = f32 out, 1 = bf16 out.
// ---------------------------------------------------------------------------
template <int SRC, int EPI, int OUTBF>
__global__ __launch_bounds__(256, 3)
void mgemm_kernel(const float* __restrict__ A, const unsigned short* __restrict__ Axp,
                  const float* __restrict__ pos,
                  const float* __restrict__ W0, const float* __restrict__ W1,
                  const float* __restrict__ b0, const float* __restrict__ b1,
                  void* __restrict__ C0v, void* __restrict__ C1v, int c0)
{
    __shared__ __align__(16) char As[128 * 192];   // 24 KB bf16 [row][k(96)]
    __shared__ __align__(16) char Bs[96 * 192];    // 18 KB bf16 [oc][k(96)]
    const int tid = threadIdx.x;
    const int gm0 = blockIdx.x * 128;
    const int gn0 = blockIdx.y * 96;
    const int wid = tid >> 6;
    const int wm = wid >> 1, wn = wid & 1;
    const int lane = tid & 63;
    const int lr = lane & 15;
    const int lk = lane >> 4;

    const bool hiN = (gn0 >= 192);
    const float* Wsel = (EPI == 3 && hiN) ? W1 : W0;
    const int wrow0 = (EPI == 3 && hiN) ? (gn0 - 192) : gn0;

    f32x4 acc[4][3];
#pragma unroll
    for (int i = 0; i < 4; i++)
#pragma unroll
        for (int j = 0; j < 3; j++) acc[i][j] = (f32x4){0.f, 0.f, 0.f, 0.f};

    for (int kb = 0; kb < 192; kb += 96) {
#pragma unroll
        for (int it = 0; it < 12; it++) {
            int f4 = tid + it * 256;
            int row = f4 / 24;
            int kc4 = (f4 - row * 24) * 4;
            float av[4];
            if (SRC == 0) {
                float4 v = *reinterpret_cast<const float4*>(
                    &A[(size_t)(gm0 + row) * 192 + kb + kc4]);
                av[0] = v.x; av[1] = v.y; av[2] = v.z; av[3] = v.w;
            } else {
                int g = gm0 + row;
                int bt, tok;
                if (SRC == 1) { bt = g >> 6; tok = g & 63; }
                else { bt = g / 320; tok = g - bt * 320; bt += c0; }
                int n = tok & 63;
                int kcol = kb + kc4;
                float4 p4 = *reinterpret_cast<const float4*>(&pos[n * 192 + kcol]);
                float pv[4] = {p4.x, p4.y, p4.z, p4.w};
                if (SRC == 2 && tok >= 64) {
                    int mm = (tok >> 6) - 1;
                    u16x4 a = *reinterpret_cast<const u16x4*>(
                        &Axp[(size_t)bt * 49152 + mm * 12288 + n * 192 + kcol]);
#pragma unroll
                    for (int jj = 0; jj < 4; jj++) av[jj] = bf2f(a[jj]) + pv[jj];
                } else {
                    size_t xb = (size_t)bt * 49152 + n * 192 + kcol;
                    u16x4 a0 = *reinterpret_cast<const u16x4*>(&Axp[xb]);
                    u16x4 a1 = *reinterpret_cast<const u16x4*>(&Axp[xb + 12288]);
                    u16x4 a2 = *reinterpret_cast<const u16x4*>(&Axp[xb + 24576]);
                    u16x4 a3 = *reinterpret_cast<const u16x4*>(&Axp[xb + 36864]);
#pragma unroll
                    for (int jj = 0; jj < 4; jj++)
                        av[jj] = 0.25f * (bf2f(a0[jj]) + bf2f(a1[jj]) +
                                          bf2f(a2[jj]) + bf2f(a3[jj])) + pv[jj];
                }
            }
            u16x4 bvv;
#pragma unroll
            for (int jj = 0; jj < 4; jj++) bvv[jj] = f2bf(av[jj]);
            int boff = (kc4 * 2) ^ ((row & 3) << 4);
            *reinterpret_cast<u16x4*>(As + row * 192 + boff) = bvv;
        }
#pragma unroll
        for (int it = 0; it < 9; it++) {
            int f4 = tid + it * 256;
            int row = f4 / 24;
            int kc4 = (f4 - row * 24) * 4;
            float4 v = *reinterpret_cast<const float4*>(
                &Wsel[(size_t)(wrow0 + row) * 192 + kb + kc4]);
            u16x4 bvv;
            bvv[0] = f2bf(v.x); bvv[1] = f2bf(v.y); bvv[2] = f2bf(v.z); bvv[3] = f2bf(v.w);
            int boff = (kc4 * 2) ^ ((row & 3) << 4);
            *reinterpret_cast<u16x4*>(Bs + row * 192 + boff) = bvv;
        }
        __syncthreads();

#pragma unroll
        for (int ks = 0; ks < 3; ks++) {
            s16x8 af[4], bf[3];
#pragma unroll
            for (int i = 0; i < 4; i++) {
                int row = wm * 64 + i * 16 + lr;
                int off = (ks * 64 + lk * 16) ^ ((row & 3) << 4);
                af[i] = *reinterpret_cast<const s16x8*>(As + row * 192 + off);
            }
#pragma unroll
            for (int j = 0; j < 3; j++) {
                int row = wn * 48 + j * 16 + lr;
                int off = (ks * 64 + lk * 16) ^ ((row & 3) << 4);
                bf[j] = *reinterpret_cast<const s16x8*>(Bs + row * 192 + off);
            }
#pragma unroll
            for (int i = 0; i < 4; i++)
#pragma unroll
                for (int j = 0; j < 3; j++)
                    acc[i][j] = __builtin_amdgcn_mfma_f32_16x16x32_bf16(
                        af[i], bf[j], acc[i][j], 0, 0, 0);
        }
        __syncthreads();
    }

#pragma unroll
    for (int j = 0; j < 3; j++) {
        int bcol = gn0 + wn * 48 + j * 16 + lr;
        float bv = (EPI == 3 && bcol >= 192) ? b1[bcol - 192] : b0[bcol];
        void* dst = C0v;
        int oc = bcol;
        if ((EPI == 2 || EPI == 3) && bcol >= 192) { dst = C1v; oc = bcol - 192; }
#pragma unroll
        for (int i = 0; i < 4; i++) {
            int rbase = gm0 + wm * 64 + i * 16 + lk * 4;
#pragma unroll
            for (int r = 0; r < 4; r++) {
                float v = acc[i][j][r] + bv;
                if (EPI == 1) v = 0.5f * v * (1.f + erff(v * 0.70710678118654752440f));
                size_t idx = (size_t)(rbase + r) * 192 + oc;
                if (OUTBF) ((unsigned short*)dst)[idx] = f2bf(v);
                else       ((float*)dst)[idx] = v;
            }
        }
    }
}

// ---------------------------------------------------------------------------
// Fused window attention, key-split (r7 PROVEN core): block = (bb,t,m),
// 768 thr = 12 waves. Wave w: head h = w>>1, keys [(w&1)*32 .. +32).
// K/V/mask/rpbT staged as F32 in LDS (149.5 KB, 1 block/CU, VGPR 80 — the
// only spill-free config, see header). Staging reads bf16 globals and
// converts (transient temps only). Pair-merge via LDS.
// ---------------------------------------------------------------------------
__global__ __launch_bounds__(768, 1)
void winattn_kernel(const float* __restrict__ qbuf,
                    const unsigned short* __restrict__ kbuf,
                    const unsigned short* __restrict__ vbuf,
                    const float* __restrict__ mask,
                    const float* __restrict__ rpbt, unsigned short* __restrict__ xp)
{
    __shared__ float klds[64 * 192];       // 48 KB
    __shared__ float vlds[64 * 192];       // 48 KB
    __shared__ float mlds[64 * 65];        // 16.25 KB
    __shared__ float rldsT[6 * 225];       // 5.3 KB  [h][ridx]
    __shared__ float exm[768];             // 3 KB
    __shared__ float exl[768];             // 3 KB
    __shared__ unsigned obuf[6 * 64 * 17]; // 25.5 KB (u32 = 2 packed bf16)
    const int tid = threadIdx.x;
    const int bid = blockIdx.x;            // bb*16 + t*4 + m
    const int bb = bid >> 4;
    const int t = (bid >> 2) & 3;
    const int m = bid & 3;
    const int w = tid >> 6;
    const int h = w >> 1;
    const int lane = tid & 63;

    const int kvbase = (bb * 4 + m) * 12288;
#pragma unroll
    for (int it = 0; it < 2; it++) {
        int i8 = tid + it * 768;           // 0..1535, 8 bf16 each
        u16x8 kq = *reinterpret_cast<const u16x8*>(&kbuf[kvbase + i8 * 8]);
        u16x8 vq = *reinterpret_cast<const u16x8*>(&vbuf[kvbase + i8 * 8]);
        f32x4 k0, k1, v0, v1;
#pragma unroll
        for (int e = 0; e < 4; e++) {
            k0[e] = bf2f(kq[e]); k1[e] = bf2f(kq[e + 4]);
            v0[e] = bf2f(vq[e]); v1[e] = bf2f(vq[e + 4]);
        }
        *reinterpret_cast<f32x4*>(&klds[i8 * 8]) = k0;
        *reinterpret_cast<f32x4*>(&klds[i8 * 8 + 4]) = k1;
        *reinterpret_cast<f32x4*>(&vlds[i8 * 8]) = v0;
        *reinterpret_cast<f32x4*>(&vlds[i8 * 8 + 4]) = v1;
    }
    const int widx = bb & 63;
    for (int f = tid; f < 4096; f += 768)
        mlds[(f >> 6) * 65 + (f & 63)] = mask[widx * 4096 + f];
    for (int f = tid; f < 1350; f += 768) {
        int hh = f / 225, rr = f - hh * 225;
        rldsT[f] = rpbt[rr * 6 + hh];
    }

    float qreg[32];
    const int qbase = ((bb * 4 + t) * 64 + lane) * 192 + h * 32;
#pragma unroll
    for (int j = 0; j < 8; j++) {
        float4 v = *reinterpret_cast<const float4*>(&qbuf[qbase + j * 4]);
        qreg[4 * j] = v.x; qreg[4 * j + 1] = v.y;
        qreg[4 * j + 2] = v.z; qreg[4 * j + 3] = v.w;
    }
    __syncthreads();

    const float scale = 0.17677669529663688110f;  // 1/sqrt(32)
    const int ni = lane >> 3, nj = lane & 7;
    const int e0 = (w & 1) << 5;
    float s[32];
#pragma unroll
    for (int ee = 0; ee < 32; ee++) {
        int e = e0 + ee;
        const float4* kr = reinterpret_cast<const float4*>(&klds[e * 192 + h * 32]);
        float d0 = 0, d1 = 0, d2 = 0, d3 = 0;
#pragma unroll
        for (int q8 = 0; q8 < 8; q8++) {
            float4 k4 = kr[q8];
            d0 += qreg[q8 * 4] * k4.x;
            d1 += qreg[q8 * 4 + 1] * k4.y;
            d2 += qreg[q8 * 4 + 2] * k4.z;
            d3 += qreg[q8 * 4 + 3] * k4.w;
        }
        int ridx = (ni - (e >> 3) + 7) * 15 + (nj - (e & 7) + 7);
        s[ee] = (d0 + d1 + d2 + d3) * scale + rldsT[h * 225 + ridx] + mlds[lane * 65 + e];
    }
    float mrun = s[0];
#pragma unroll
    for (int ee = 1; ee < 32; ee++) mrun = fmaxf(mrun, s[ee]);
    float lrun = 0.f;
#pragma unroll
    for (int ee = 0; ee < 32; ee++) { s[ee] = __expf(s[ee] - mrun); lrun += s[ee]; }

    float o[32];
#pragma unroll
    for (int d = 0; d < 32; d++) o[d] = 0.f;
#pragma unroll
    for (int ee = 0; ee < 32; ee++) {
        float p = s[ee];
        const float4* vr = reinterpret_cast<const float4*>(&vlds[(e0 + ee) * 192 + h * 32]);
#pragma unroll
        for (int d8 = 0; d8 < 8; d8++) {
            float4 v4 = vr[d8];
            o[d8 * 4] += p * v4.x; o[d8 * 4 + 1] += p * v4.y;
            o[d8 * 4 + 2] += p * v4.z; o[d8 * 4 + 3] += p * v4.w;
        }
    }

    // ---- pair merge: waves (2h, 2h+1) ----
    __syncthreads();
    exm[w * 64 + lane] = mrun;
    __syncthreads();
    float mo = exm[(w ^ 1) * 64 + lane];
    float mt = fmaxf(mrun, mo);
    float fs = __expf(mrun - mt);
    if (w & 1) {
        unsigned* ob = &obuf[h * 1088 + lane * 17];
#pragma unroll
        for (int j = 0; j < 16; j++) {
            unsigned lo = f2bf(fs * o[2 * j]);
            unsigned hi = f2bf(fs * o[2 * j + 1]);
            ob[j] = lo | (hi << 16);
        }
        exl[w * 64 + lane] = fs * lrun;
    }
    __syncthreads();
    if (!(w & 1)) {
        float lt = fs * lrun + exl[(w + 1) * 64 + lane];
        const float inv = 1.f / lt;
        const unsigned* ob = &obuf[h * 1088 + lane * 17];
        const int obase = bb * 196608 + m * 49152 + t * 12288 + h * 2048 + lane * 32;
#pragma unroll
        for (int j = 0; j < 8; j++) {
            unsigned p0 = ob[2 * j], p1 = ob[2 * j + 1];
            u16x4 v;
            v[0] = f2bf((fs * o[4 * j]     + bf2f((unsigned short)(p0 & 0xffff))) * inv);
            v[1] = f2bf((fs * o[4 * j + 1] + bf2f((unsigned short)(p0 >> 16))) * inv);
            v[2] = f2bf((fs * o[4 * j + 2] + bf2f((unsigned short)(p1 & 0xffff))) * inv);
            v[3] = f2bf((fs * o[4 * j + 3] + bf2f((unsigned short)(p1 >> 16))) * inv);
            *reinterpret_cast<u16x4*>(&xp[obase + j * 4]) = v;
        }
    }
}

// ---------------------------------------------------------------------------
// Pooling attention (r7 known-good f32-LDS version): block = (h, btl),
// 320 threads = 5 waves. Wave w handles key tiles {w, w+5} of 10 (32 keys)
// with private online softmax; partials merged via LDS.
// ---------------------------------------------------------------------------
__global__ __launch_bounds__(320)
void poolattn3_kernel(const unsigned short* __restrict__ kk,
                      const unsigned short* __restrict__ vv,
                      const float* __restrict__ qq, float* __restrict__ opool, int c0)
{
    __shared__ float ubuf[10560];      // union: K/V slots (w*2048) | sco (w*2112+q*33+d)
    __shared__ float scm[320], scl[320];
    const int tid = threadIdx.x;
    const int w = tid >> 6, lane = tid & 63;
    const int h = blockIdx.x, btl = blockIdx.y;
    const int bt = c0 + btl;
    float* Kf = ubuf + w * 2048;
    float* Vf = Kf + 1024;

    float qreg[32];
    const size_t qbase = (size_t)(bt * 64 + lane) * 192 + h * 32;
#pragma unroll
    for (int j = 0; j < 8; j++) {
        float4 v = *reinterpret_cast<const float4*>(&qq[qbase + j * 4]);
        qreg[4 * j] = v.x; qreg[4 * j + 1] = v.y;
        qreg[4 * j + 2] = v.z; qreg[4 * j + 3] = v.w;
    }
    const float scale = 0.17677669529663688110f;
    float mrun = -3.0e38f, lrun = 0.f;
    float o[32];
#pragma unroll
    for (int d = 0; d < 32; d++) o[d] = 0.f;

#pragma unroll
    for (int it = 0; it < 2; it++) {
        const int tt = w + it * 5;
        const unsigned short* ks = kk + (size_t)(btl * 320 + tt * 32) * 192 + h * 32;
        const unsigned short* vs = vv + (size_t)(btl * 320 + tt * 32) * 192 + h * 32;
#pragma unroll
        for (int ci = 0; ci < 2; ci++) {
            int idx = lane + ci * 64;          // 0..127
            int j = idx >> 2, q4 = (idx & 3) * 8;
            s16x8 kv8 = *reinterpret_cast<const s16x8*>(&ks[j * 192 + q4]);
            s16x8 vv8 = *reinterpret_cast<const s16x8*>(&vs[j * 192 + q4]);
            f32x4 lo, hi, vlo, vhi;
#pragma unroll
            for (int e = 0; e < 4; e++) {
                lo[e] = bf2f((unsigned short)kv8[e]);
                hi[e] = bf2f((unsigned short)kv8[e + 4]);
                vlo[e] = bf2f((unsigned short)vv8[e]);
                vhi[e] = bf2f((unsigned short)vv8[e + 4]);
            }
            *reinterpret_cast<f32x4*>(Kf + j * 32 + q4) = lo;
            *reinterpret_cast<f32x4*>(Kf + j * 32 + q4 + 4) = hi;
            *reinterpret_cast<f32x4*>(Vf + j * 32 + q4) = vlo;
            *reinterpret_cast<f32x4*>(Vf + j * 32 + q4 + 4) = vhi;
        }
        float s[32];
#pragma unroll
        for (int j = 0; j < 32; j++) {
            const float4* kr = reinterpret_cast<const float4*>(Kf + j * 32);
            float d0 = 0, d1 = 0, d2 = 0, d3 = 0;
#pragma unroll
            for (int q8 = 0; q8 < 8; q8++) {
                float4 k4 = kr[q8];
                d0 += qreg[q8 * 4] * k4.x;
                d1 += qreg[q8 * 4 + 1] * k4.y;
                d2 += qreg[q8 * 4 + 2] * k4.z;
                d3 += qreg[q8 * 4 + 3] * k4.w;
            }
            s[j] = (d0 + d1 + d2 + d3) * scale;
        }
        float mt = s[0];
#pragma unroll
        for (int j = 1; j < 32; j++) mt = fmaxf(mt, s[j]);
        float mnew = fmaxf(mrun, mt);
        float fct = __expf(mrun - mnew);
        lrun *= fct;
#pragma unroll
        for (int d = 0; d < 32; d++) o[d] *= fct;
#pragma unroll
        for (int j = 0; j < 32; j++) { float p = __expf(s[j] - mnew); lrun += p; s[j] = p; }
#pragma unroll
        for (int j = 0; j < 32; j++) {
            float p = s[j];
            const float4* vr = reinterpret_cast<const float4*>(Vf + j * 32);
#pragma unroll
            for (int d8 = 0; d8 < 8; d8++) {
                float4 v4 = vr[d8];
                o[d8 * 4] += p * v4.x; o[d8 * 4 + 1] += p * v4.y;
                o[d8 * 4 + 2] += p * v4.z; o[d8 * 4 + 3] += p * v4.w;
            }
        }
        mrun = mnew;
    }
    __syncthreads();                 // everyone done with K/V region
    scm[w * 64 + lane] = mrun;
    scl[w * 64 + lane] = lrun;
#pragma unroll
    for (int d = 0; d < 32; d++) ubuf[w * 2112 + lane * 33 + d] = o[d];
    __syncthreads();

    if (w == 0) {
        float m5 = scm[lane];
#pragma unroll
        for (int ww = 1; ww < 5; ww++) m5 = fmaxf(m5, scm[ww * 64 + lane]);
        float den = 0.f;
        float od[32];
#pragma unroll
        for (int d = 0; d < 32; d++) od[d] = 0.f;
#pragma unroll
        for (int ww = 0; ww < 5; ww++) {
            float f = __expf(scm[ww * 64 + lane] - m5);
            den += f * scl[ww * 64 + lane];
            const float* src = ubuf + ww * 2112 + lane * 33;
#pragma unroll
            for (int d = 0; d < 32; d++) od[d] += f * src[d];
        }
        const float inv = 1.f / den;
        const size_t ob = (size_t)(bt * 64 + lane) * 192 + h * 32;
#pragma unroll
        for (int j = 0; j < 8; j++) {
            float4 v;
            v.x = od[4 * j] * inv; v.y = od[4 * j + 1] * inv;
            v.z = od[4 * j + 2] * inv; v.w = od[4 * j + 3] * inv;
            *reinterpret_cast<float4*>(&opool[ob + j * 4]) = v;
        }
    }
}

extern "C" void kernel_launch(void* const* d_in, const int* in_sizes, int n_in,
                              void* d_out, int out_size, void* d_ws, size_t ws_size,
                              hipStream_t stream) {
    (void)in_sizes; (void)n_in; (void)out_size; (void)ws_size;
    const float* x      = (const float*)d_in[0];
    const float* x_kv   = (const float*)d_in[1];
    const float* mask   = (const float*)d_in[2];
    const float* rpbt   = (const float*)d_in[3];
    const float* q_w    = (const float*)d_in[4];
    const float* q_b    = (const float*)d_in[5];
    const float* kv_w   = (const float*)d_in[6];
    const float* kv_b   = (const float*)d_in[7];
    const float* pos    = (const float*)d_in[8];
    const float* pq_w   = (const float*)d_in[9];
    const float* pq_b   = (const float*)d_in[10];
    const float* pk_w   = (const float*)d_in[11];
    const float* pk_b   = (const float*)d_in[12];
    const float* pv_w   = (const float*)d_in[13];
    const float* pv_b   = (const float*)d_in[14];
    const float* po_w   = (const float*)d_in[15];
    const float* po_b   = (const float*)d_in[16];
    const float* proj_w = (const float*)d_in[17];
    const float* proj_b = (const float*)d_in[18];
    float* out = (float*)d_out;
    char* ws = (char*)d_ws;

    float*          qbuf = (float*)(ws);                       // 24 MB
    unsigned short* xp   = (unsigned short*)(ws + 25165824u);  // 48 MB bf16
    unsigned short* kbuf = (unsigned short*)(ws + 75497472u);  // 12 MB bf16
    unsigned short* vbuf = (unsigned short*)(ws + 88080384u);  // 12 MB bf16
    float*          qq   = qbuf;
    unsigned short* kkc  = (unsigned short*)(ws + 75497472u);  // 31.5 MB / chunk
    unsigned short* vvc  = (unsigned short*)(ws + 106954752u); // 31.5 MB / chunk
    float*          opo  = (float*)(ws + 75497472u);           // after pooling
    float*          opool = out;                               // d_out as scratch

    dim3 blk(256);
    // q = x @ q_w^T + q_b
    mgemm_kernel<0, 0, 0><<<dim3(256, 2), blk, 0, stream>>>(
        x, nullptr, nullptr, q_w, nullptr, q_b, nullptr, qbuf, nullptr, 0);
    // k,v = x_kv @ kv_w^T + kv_b  (split at oc 192, bf16 out)
    mgemm_kernel<0, 2, 1><<<dim3(256, 4), blk, 0, stream>>>(
        x_kv, nullptr, nullptr, kv_w, nullptr, kv_b, nullptr, kbuf, vbuf, 0);
    winattn_kernel<<<2048, 768, 0, stream>>>(qbuf, kbuf, vbuf, mask, rpbt, xp);
    // qq = (mean_m xp + pos) @ pq_w^T + pq_b
    mgemm_kernel<1, 0, 0><<<dim3(256, 2), blk, 0, stream>>>(
        nullptr, xp, pos, pq_w, nullptr, pq_b, nullptr, qq, nullptr, 0);
    // pooling in 2 chunks of 256 bt
    for (int c0 = 0; c0 < 512; c0 += 256) {
        mgemm_kernel<2, 3, 1><<<dim3(640, 4), blk, 0, stream>>>(
            nullptr, xp, pos, pk_w, pv_w, pk_b, pv_b, kkc, vvc, c0);
        poolattn3_kernel<<<dim3(6, 256), 320, 0, stream>>>(kkc, vvc, qq, opool, c0);
    }
    // opo = gelu(opool @ po_w^T + po_b); out = opo @ proj_w^T + proj_b
    mgemm_kernel<0, 1, 0><<<dim3(256, 2), blk, 0, stream>>>(
        opool, nullptr, nullptr, po_w, nullptr, po_b, nullptr, opo, nullptr, 0);
    mgemm_kernel<0, 0, 0><<<dim3(256, 2), blk, 0, stream>>>(
        opo, nullptr, nullptr, proj_w, nullptr, proj_b, nullptr, out, nullptr, 0);
}

// Round 14
// 653.356 us; speedup vs baseline: 1.9894x; 1.2269x over previous
//
#include <hip/hip_runtime.h>
#include <math.h>

// ---------------------------------------------------------------------------
// MultiReferenceWindowAttention — bf16-MFMA GEMMs (pure-copy staging) + attn.
// B_=128, T=4, M=4, N=64, C=192, nH=6, hd=32, BT=512
// Workspace (<= proven 177,340,416 B):
//   qbuf f32  @ 0        24 MB   q -> later qq
//   xp  bf16  @ 24 MB    48 MB   (prep adds pos in place -> xp2)
//   kbuf bf16 @ 72 MB    12 MB   k (dead after winattn) -> kkc chunk
//   vbuf bf16 @ 84 MB    12 MB   v (dead after winattn)
//   kkc bf16  @ 72 MB    30 MB/chunk ; vvc bf16 @ 102 MB  30 MB/chunk
//   t0b bf16  @ 132 MB   12.6 MB (avg tokens + pos)
//   opoolb    @ 144 MB   12.6 MB (pool attn out, bf16)
//   opob      @ 156 MB   12.6 MB (gelu out, bf16)
//   wbf       @ 168 MB   0.59 MB (all 7 weights bf16, packed)
// peak = 176,750,592 B.
//
// VGPR/SPILL MODEL (r7..r13, settled): hipcc targets ~84 VGPR for 768-thread
// blocks and SPILLS rather than exceed it. winattn's f32-LDS core fits at 80
// (zero spill); bf16-unpack variants need ~96+ -> 1.7-2.9 GB scratch. KEEP
// the f32 core. GEMM lesson (r13): staging f32->bf16 cvt was 2x the MFMA
// time; this round makes all hot-path staging pure u16x8 copies.
// ---------------------------------------------------------------------------

typedef float f32x4 __attribute__((ext_vector_type(4)));
typedef short s16x8 __attribute__((ext_vector_type(8)));
typedef unsigned short u16x4 __attribute__((ext_vector_type(4)));
typedef unsigned short u16x8 __attribute__((ext_vector_type(8)));

__device__ __forceinline__ unsigned short f2bf(float f) {
    union { float f; unsigned u; } c; c.f = f;
    return (unsigned short)((c.u + 0x7fffu + ((c.u >> 16) & 1u)) >> 16);
}
__device__ __forceinline__ float bf2f(unsigned short h) {
    union { unsigned u; float f; } c; c.u = ((unsigned)h) << 16;
    return c.f;
}

// ---- all 7 weights -> packed bf16 (element offsets: q 0, kv 36864,
// pq 110592, pk 147456, pv 184320, po 221184, proj 258048; total 294912)
__global__ void wcvt_kernel(const float* __restrict__ q_w, const float* __restrict__ kv_w,
                            const float* __restrict__ pq_w, const float* __restrict__ pk_w,
                            const float* __restrict__ pv_w, const float* __restrict__ po_w,
                            const float* __restrict__ proj_w, unsigned short* __restrict__ wbf)
{
    int i = blockIdx.x * 256 + threadIdx.x;
    if (i >= 294912) return;
    const float* src; int off;
    if      (i < 36864)  { src = q_w;    off = 0; }
    else if (i < 110592) { src = kv_w;   off = 36864; }
    else if (i < 147456) { src = pq_w;   off = 110592; }
    else if (i < 184320) { src = pk_w;   off = 147456; }
    else if (i < 221184) { src = pv_w;   off = 184320; }
    else if (i < 258048) { src = po_w;   off = 221184; }
    else                 { src = proj_w; off = 258048; }
    wbf[i] = f2bf(src[i - off]);
}

// ---- prep: xp += pos (in place, bf16) and t0 = mean_m(xp)+pos (bf16)
__global__ void prep_kernel(unsigned short* __restrict__ xp, const float* __restrict__ pos,
                            unsigned short* __restrict__ t0b)
{
    int i = blockIdx.x * 256 + threadIdx.x;   // 786432 total
    int c8 = (i % 24) * 8;
    int n  = (i / 24) & 63;
    int bt = i / (24 * 64);
    float4 p0 = *reinterpret_cast<const float4*>(&pos[n * 192 + c8]);
    float4 p1 = *reinterpret_cast<const float4*>(&pos[n * 192 + c8 + 4]);
    float pv[8] = {p0.x, p0.y, p0.z, p0.w, p1.x, p1.y, p1.z, p1.w};
    float acc[8] = {0, 0, 0, 0, 0, 0, 0, 0};
    size_t base = (size_t)bt * 49152 + n * 192 + c8;
#pragma unroll
    for (int m = 0; m < 4; m++) {
        u16x8 v = *reinterpret_cast<const u16x8*>(&xp[base + m * 12288]);
        u16x8 o;
#pragma unroll
        for (int e = 0; e < 8; e++) {
            float f = bf2f(v[e]) + pv[e];
            acc[e] += f;
            o[e] = f2bf(f);
        }
        *reinterpret_cast<u16x8*>(&xp[base + m * 12288]) = o;
    }
    u16x8 t;
#pragma unroll
    for (int e = 0; e < 8; e++) t[e] = f2bf(acc[e] * 0.25f);
    *reinterpret_cast<u16x8*>(&t0b[(size_t)(bt * 64 + n) * 192 + c8]) = t;
}

// ---------------------------------------------------------------------------
// MFMA bf16 GEMM:  C[row, oc] = sum_k Arow[k] * W[oc][k] + bias[oc]
// Block tile 128 rows x 96 oc, K=192 staged in 2 halves of 96. Weights bf16.
// SRC: 0 = A f32 rows (cvt); 3 = Ab bf16 row-major (pure copy);
//      4 = seq rows: g -> (bt=c0+g/320, tok); tok<64 -> Ab2(t0b) else Ab(xp2).
// EPI: 0 plain, 1 exact gelu, 2 split oc@192 (b0 len 384), 3 split (W1,b1).
// OUTBF: 0 f32 out, 1 bf16 out.
// ---------------------------------------------------------------------------
template <int SRC, int EPI, int OUTBF>
__global__ __launch_bounds__(256, 3)
void mgemm_kernel(const float* __restrict__ A, const unsigned short* __restrict__ Ab,
                  const unsigned short* __restrict__ Ab2,
                  const unsigned short* __restrict__ W0, const unsigned short* __restrict__ W1,
                  const float* __restrict__ b0, const float* __restrict__ b1,
                  void* __restrict__ C0v, void* __restrict__ C1v, int c0)
{
    __shared__ __align__(16) char As[128 * 192];   // 24 KB bf16 [row][k(96)]
    __shared__ __align__(16) char Bs[96 * 192];    // 18 KB bf16 [oc][k(96)]
    const int tid = threadIdx.x;
    const int gm0 = blockIdx.x * 128;
    const int gn0 = blockIdx.y * 96;
    const int wid = tid >> 6;
    const int wm = wid >> 1, wn = wid & 1;
    const int lane = tid & 63;
    const int lr = lane & 15;
    const int lk = lane >> 4;

    const bool hiN = (gn0 >= 192);
    const unsigned short* Wsel = (EPI == 3 && hiN) ? W1 : W0;
    const int wrow0 = (EPI == 3 && hiN) ? (gn0 - 192) : gn0;

    f32x4 acc[4][3];
#pragma unroll
    for (int i = 0; i < 4; i++)
#pragma unroll
        for (int j = 0; j < 3; j++) acc[i][j] = (f32x4){0.f, 0.f, 0.f, 0.f};

    for (int kb = 0; kb < 192; kb += 96) {
        // ---- stage A ----
        if (SRC == 0) {
#pragma unroll
            for (int it = 0; it < 12; it++) {
                int f4 = tid + it * 256;
                int row = f4 / 24;
                int kc4 = (f4 - row * 24) * 4;
                float4 v = *reinterpret_cast<const float4*>(
                    &A[(size_t)(gm0 + row) * 192 + kb + kc4]);
                u16x4 bvv;
                bvv[0] = f2bf(v.x); bvv[1] = f2bf(v.y);
                bvv[2] = f2bf(v.z); bvv[3] = f2bf(v.w);
                int boff = (kc4 * 2) ^ ((row & 3) << 4);
                *reinterpret_cast<u16x4*>(As + row * 192 + boff) = bvv;
            }
        } else {
#pragma unroll
            for (int it = 0; it < 6; it++) {
                int f8 = tid + it * 256;
                int row = f8 / 12;
                int c16 = f8 - row * 12;
                const unsigned short* src;
                if (SRC == 3) {
                    src = &Ab[(size_t)(gm0 + row) * 192 + kb + c16 * 8];
                } else {
                    int g = gm0 + row;
                    int bt = g / 320, tok = g - bt * 320; bt += c0;
                    src = (tok < 64)
                        ? &Ab2[(size_t)(bt * 64 + tok) * 192 + kb + c16 * 8]
                        : &Ab[(size_t)bt * 49152 + ((tok >> 6) - 1) * 12288
                              + (tok & 63) * 192 + kb + c16 * 8];
                }
                u16x8 v = *reinterpret_cast<const u16x8*>(src);
                int boff = (c16 * 16) ^ ((row & 3) << 4);
                *reinterpret_cast<u16x8*>(As + row * 192 + boff) = v;
            }
        }
        // ---- stage B: 96 oc-rows x 96 k, pure bf16 copy ----
        for (int f8 = tid; f8 < 1152; f8 += 256) {
            int row = f8 / 12;
            int c16 = f8 - row * 12;
            u16x8 v = *reinterpret_cast<const u16x8*>(
                &Wsel[(size_t)(wrow0 + row) * 192 + kb + c16 * 8]);
            int boff = (c16 * 16) ^ ((row & 3) << 4);
            *reinterpret_cast<u16x8*>(Bs + row * 192 + boff) = v;
        }
        __syncthreads();

#pragma unroll
        for (int ks = 0; ks < 3; ks++) {
            s16x8 af[4], bf[3];
#pragma unroll
            for (int i = 0; i < 4; i++) {
                int row = wm * 64 + i * 16 + lr;
                int off = (ks * 64 + lk * 16) ^ ((row & 3) << 4);
                af[i] = *reinterpret_cast<const s16x8*>(As + row * 192 + off);
            }
#pragma unroll
            for (int j = 0; j < 3; j++) {
                int row = wn * 48 + j * 16 + lr;
                int off = (ks * 64 + lk * 16) ^ ((row & 3) << 4);
                bf[j] = *reinterpret_cast<const s16x8*>(Bs + row * 192 + off);
            }
#pragma unroll
            for (int i = 0; i < 4; i++)
#pragma unroll
                for (int j = 0; j < 3; j++)
                    acc[i][j] = __builtin_amdgcn_mfma_f32_16x16x32_bf16(
                        af[i], bf[j], acc[i][j], 0, 0, 0);
        }
        __syncthreads();
    }

#pragma unroll
    for (int j = 0; j < 3; j++) {
        int bcol = gn0 + wn * 48 + j * 16 + lr;
        float bv = (EPI == 3 && bcol >= 192) ? b1[bcol - 192] : b0[bcol];
        void* dst = C0v;
        int oc = bcol;
        if ((EPI == 2 || EPI == 3) && bcol >= 192) { dst = C1v; oc = bcol - 192; }
#pragma unroll
        for (int i = 0; i < 4; i++) {
            int rbase = gm0 + wm * 64 + i * 16 + lk * 4;
#pragma unroll
            for (int r = 0; r < 4; r++) {
                float v = acc[i][j][r] + bv;
                if (EPI == 1) v = 0.5f * v * (1.f + erff(v * 0.70710678118654752440f));
                size_t idx = (size_t)(rbase + r) * 192 + oc;
                if (OUTBF) ((unsigned short*)dst)[idx] = f2bf(v);
                else       ((float*)dst)[idx] = v;
            }
        }
    }
}

// ---------------------------------------------------------------------------
// Fused window attention, key-split (r7 PROVEN core, VGPR 80, no spill):
// block = (bb,t,m), 768 thr = 12 waves. Wave w: head h = w>>1, keys
// [(w&1)*32 .. +32). K/V/mask/rpbT staged F32 in LDS (149.5 KB, 1 blk/CU).
// Staging reads bf16 globals and converts (transient temps only).
// ---------------------------------------------------------------------------
__global__ __launch_bounds__(768, 1)
void winattn_kernel(const float* __restrict__ qbuf,
                    const unsigned short* __restrict__ kbuf,
                    const unsigned short* __restrict__ vbuf,
                    const float* __restrict__ mask,
                    const float* __restrict__ rpbt, unsigned short* __restrict__ xp)
{
    __shared__ float klds[64 * 192];       // 48 KB
    __shared__ float vlds[64 * 192];       // 48 KB
    __shared__ float mlds[64 * 65];        // 16.25 KB
    __shared__ float rldsT[6 * 225];       // 5.3 KB  [h][ridx]
    __shared__ float exm[768];
    __shared__ float exl[768];
    __shared__ unsigned obuf[6 * 64 * 17]; // 25.5 KB
    const int tid = threadIdx.x;
    const int bid = blockIdx.x;            // bb*16 + t*4 + m
    const int bb = bid >> 4;
    const int t = (bid >> 2) & 3;
    const int m = bid & 3;
    const int w = tid >> 6;
    const int h = w >> 1;
    const int lane = tid & 63;

    const int kvbase = (bb * 4 + m) * 12288;
#pragma unroll
    for (int it = 0; it < 2; it++) {
        int i8 = tid + it * 768;
        u16x8 kq = *reinterpret_cast<const u16x8*>(&kbuf[kvbase + i8 * 8]);
        u16x8 vq = *reinterpret_cast<const u16x8*>(&vbuf[kvbase + i8 * 8]);
        f32x4 k0, k1, v0, v1;
#pragma unroll
        for (int e = 0; e < 4; e++) {
            k0[e] = bf2f(kq[e]); k1[e] = bf2f(kq[e + 4]);
            v0[e] = bf2f(vq[e]); v1[e] = bf2f(vq[e + 4]);
        }
        *reinterpret_cast<f32x4*>(&klds[i8 * 8]) = k0;
        *reinterpret_cast<f32x4*>(&klds[i8 * 8 + 4]) = k1;
        *reinterpret_cast<f32x4*>(&vlds[i8 * 8]) = v0;
        *reinterpret_cast<f32x4*>(&vlds[i8 * 8 + 4]) = v1;
    }
    const int widx = bb & 63;
    for (int f = tid; f < 4096; f += 768)
        mlds[(f >> 6) * 65 + (f & 63)] = mask[widx * 4096 + f];
    for (int f = tid; f < 1350; f += 768) {
        int hh = f / 225, rr = f - hh * 225;
        rldsT[f] = rpbt[rr * 6 + hh];
    }

    float qreg[32];
    const int qbase = ((bb * 4 + t) * 64 + lane) * 192 + h * 32;
#pragma unroll
    for (int j = 0; j < 8; j++) {
        float4 v = *reinterpret_cast<const float4*>(&qbuf[qbase + j * 4]);
        qreg[4 * j] = v.x; qreg[4 * j + 1] = v.y;
        qreg[4 * j + 2] = v.z; qreg[4 * j + 3] = v.w;
    }
    __syncthreads();

    const float scale = 0.17677669529663688110f;  // 1/sqrt(32)
    const int ni = lane >> 3, nj = lane & 7;
    const int e0 = (w & 1) << 5;
    float s[32];
#pragma unroll
    for (int ee = 0; ee < 32; ee++) {
        int e = e0 + ee;
        const float4* kr = reinterpret_cast<const float4*>(&klds[e * 192 + h * 32]);
        float d0 = 0, d1 = 0, d2 = 0, d3 = 0;
#pragma unroll
        for (int q8 = 0; q8 < 8; q8++) {
            float4 k4 = kr[q8];
            d0 += qreg[q8 * 4] * k4.x;
            d1 += qreg[q8 * 4 + 1] * k4.y;
            d2 += qreg[q8 * 4 + 2] * k4.z;
            d3 += qreg[q8 * 4 + 3] * k4.w;
        }
        int ridx = (ni - (e >> 3) + 7) * 15 + (nj - (e & 7) + 7);
        s[ee] = (d0 + d1 + d2 + d3) * scale + rldsT[h * 225 + ridx] + mlds[lane * 65 + e];
    }
    float mrun = s[0];
#pragma unroll
    for (int ee = 1; ee < 32; ee++) mrun = fmaxf(mrun, s[ee]);
    float lrun = 0.f;
#pragma unroll
    for (int ee = 0; ee < 32; ee++) { s[ee] = __expf(s[ee] - mrun); lrun += s[ee]; }

    float o[32];
#pragma unroll
    for (int d = 0; d < 32; d++) o[d] = 0.f;
#pragma unroll
    for (int ee = 0; ee < 32; ee++) {
        float p = s[ee];
        const float4* vr = reinterpret_cast<const float4*>(&vlds[(e0 + ee) * 192 + h * 32]);
#pragma unroll
        for (int d8 = 0; d8 < 8; d8++) {
            float4 v4 = vr[d8];
            o[d8 * 4] += p * v4.x; o[d8 * 4 + 1] += p * v4.y;
            o[d8 * 4 + 2] += p * v4.z; o[d8 * 4 + 3] += p * v4.w;
        }
    }

    // ---- pair merge: waves (2h, 2h+1) ----
    __syncthreads();
    exm[w * 64 + lane] = mrun;
    __syncthreads();
    float mo = exm[(w ^ 1) * 64 + lane];
    float mt = fmaxf(mrun, mo);
    float fs = __expf(mrun - mt);
    if (w & 1) {
        unsigned* ob = &obuf[h * 1088 + lane * 17];
#pragma unroll
        for (int j = 0; j < 16; j++) {
            unsigned lo = f2bf(fs * o[2 * j]);
            unsigned hi = f2bf(fs * o[2 * j + 1]);
            ob[j] = lo | (hi << 16);
        }
        exl[w * 64 + lane] = fs * lrun;
    }
    __syncthreads();
    if (!(w & 1)) {
        float lt = fs * lrun + exl[(w + 1) * 64 + lane];
        const float inv = 1.f / lt;
        const unsigned* ob = &obuf[h * 1088 + lane * 17];
        const int obase = bb * 196608 + m * 49152 + t * 12288 + h * 2048 + lane * 32;
#pragma unroll
        for (int j = 0; j < 8; j++) {
            unsigned p0 = ob[2 * j], p1 = ob[2 * j + 1];
            u16x4 v;
            v[0] = f2bf((fs * o[4 * j]     + bf2f((unsigned short)(p0 & 0xffff))) * inv);
            v[1] = f2bf((fs * o[4 * j + 1] + bf2f((unsigned short)(p0 >> 16))) * inv);
            v[2] = f2bf((fs * o[4 * j + 2] + bf2f((unsigned short)(p1 & 0xffff))) * inv);
            v[3] = f2bf((fs * o[4 * j + 3] + bf2f((unsigned short)(p1 >> 16))) * inv);
            *reinterpret_cast<u16x4*>(&xp[obase + j * 4]) = v;
        }
    }
}

// ---------------------------------------------------------------------------
// Pooling attention (r7 known-good f32-LDS core; output now bf16):
// block = (h, btl), 320 threads = 5 waves; wave w handles key tiles {w, w+5}.
// ---------------------------------------------------------------------------
__global__ __launch_bounds__(320)
void poolattn3_kernel(const unsigned short* __restrict__ kk,
                      const unsigned short* __restrict__ vv,
                      const float* __restrict__ qq,
                      unsigned short* __restrict__ opool, int c0)
{
    __shared__ float ubuf[10560];
    __shared__ float scm[320], scl[320];
    const int tid = threadIdx.x;
    const int w = tid >> 6, lane = tid & 63;
    const int h = blockIdx.x, btl = blockIdx.y;
    const int bt = c0 + btl;
    float* Kf = ubuf + w * 2048;
    float* Vf = Kf + 1024;

    float qreg[32];
    const size_t qbase = (size_t)(bt * 64 + lane) * 192 + h * 32;
#pragma unroll
    for (int j = 0; j < 8; j++) {
        float4 v = *reinterpret_cast<const float4*>(&qq[qbase + j * 4]);
        qreg[4 * j] = v.x; qreg[4 * j + 1] = v.y;
        qreg[4 * j + 2] = v.z; qreg[4 * j + 3] = v.w;
    }
    const float scale = 0.17677669529663688110f;
    float mrun = -3.0e38f, lrun = 0.f;
    float o[32];
#pragma unroll
    for (int d = 0; d < 32; d++) o[d] = 0.f;

#pragma unroll
    for (int it = 0; it < 2; it++) {
        const int tt = w + it * 5;
        const unsigned short* ks = kk + (size_t)(btl * 320 + tt * 32) * 192 + h * 32;
        const unsigned short* vs = vv + (size_t)(btl * 320 + tt * 32) * 192 + h * 32;
#pragma unroll
        for (int ci = 0; ci < 2; ci++) {
            int idx = lane + ci * 64;
            int j = idx >> 2, q4 = (idx & 3) * 8;
            s16x8 kv8 = *reinterpret_cast<const s16x8*>(&ks[j * 192 + q4]);
            s16x8 vv8 = *reinterpret_cast<const s16x8*>(&vs[j * 192 + q4]);
            f32x4 lo, hi, vlo, vhi;
#pragma unroll
            for (int e = 0; e < 4; e++) {
                lo[e] = bf2f((unsigned short)kv8[e]);
                hi[e] = bf2f((unsigned short)kv8[e + 4]);
                vlo[e] = bf2f((unsigned short)vv8[e]);
                vhi[e] = bf2f((unsigned short)vv8[e + 4]);
            }
            *reinterpret_cast<f32x4*>(Kf + j * 32 + q4) = lo;
            *reinterpret_cast<f32x4*>(Kf + j * 32 + q4 + 4) = hi;
            *reinterpret_cast<f32x4*>(Vf + j * 32 + q4) = vlo;
            *reinterpret_cast<f32x4*>(Vf + j * 32 + q4 + 4) = vhi;
        }
        float s[32];
#pragma unroll
        for (int j = 0; j < 32; j++) {
            const float4* kr = reinterpret_cast<const float4*>(Kf + j * 32);
            float d0 = 0, d1 = 0, d2 = 0, d3 = 0;
#pragma unroll
            for (int q8 = 0; q8 < 8; q8++) {
                float4 k4 = kr[q8];
                d0 += qreg[q8 * 4] * k4.x;
                d1 += qreg[q8 * 4 + 1] * k4.y;
                d2 += qreg[q8 * 4 + 2] * k4.z;
                d3 += qreg[q8 * 4 + 3] * k4.w;
            }
            s[j] = (d0 + d1 + d2 + d3) * scale;
        }
        float mt = s[0];
#pragma unroll
        for (int j = 1; j < 32; j++) mt = fmaxf(mt, s[j]);
        float mnew = fmaxf(mrun, mt);
        float fct = __expf(mrun - mnew);
        lrun *= fct;
#pragma unroll
        for (int d = 0; d < 32; d++) o[d] *= fct;
#pragma unroll
        for (int j = 0; j < 32; j++) { float p = __expf(s[j] - mnew); lrun += p; s[j] = p; }
#pragma unroll
        for (int j = 0; j < 32; j++) {
            float p = s[j];
            const float4* vr = reinterpret_cast<const float4*>(Vf + j * 32);
#pragma unroll
            for (int d8 = 0; d8 < 8; d8++) {
                float4 v4 = vr[d8];
                o[d8 * 4] += p * v4.x; o[d8 * 4 + 1] += p * v4.y;
                o[d8 * 4 + 2] += p * v4.z; o[d8 * 4 + 3] += p * v4.w;
            }
        }
        mrun = mnew;
    }
    __syncthreads();
    scm[w * 64 + lane] = mrun;
    scl[w * 64 + lane] = lrun;
#pragma unroll
    for (int d = 0; d < 32; d++) ubuf[w * 2112 + lane * 33 + d] = o[d];
    __syncthreads();

    if (w == 0) {
        float m5 = scm[lane];
#pragma unroll
        for (int ww = 1; ww < 5; ww++) m5 = fmaxf(m5, scm[ww * 64 + lane]);
        float den = 0.f;
        float od[32];
#pragma unroll
        for (int d = 0; d < 32; d++) od[d] = 0.f;
#pragma unroll
        for (int ww = 0; ww < 5; ww++) {
            float f = __expf(scm[ww * 64 + lane] - m5);
            den += f * scl[ww * 64 + lane];
            const float* src = ubuf + ww * 2112 + lane * 33;
#pragma unroll
            for (int d = 0; d < 32; d++) od[d] += f * src[d];
        }
        const float inv = 1.f / den;
        const size_t ob = (size_t)(bt * 64 + lane) * 192 + h * 32;
#pragma unroll
        for (int j = 0; j < 8; j++) {
            u16x4 v;
            v[0] = f2bf(od[4 * j] * inv);     v[1] = f2bf(od[4 * j + 1] * inv);
            v[2] = f2bf(od[4 * j + 2] * inv); v[3] = f2bf(od[4 * j + 3] * inv);
            *reinterpret_cast<u16x4*>(&opool[ob + j * 4]) = v;
        }
    }
}

extern "C" void kernel_launch(void* const* d_in, const int* in_sizes, int n_in,
                              void* d_out, int out_size, void* d_ws, size_t ws_size,
                              hipStream_t stream) {
    (void)in_sizes; (void)n_in; (void)out_size; (void)ws_size;
    const float* x      = (const float*)d_in[0];
    const float* x_kv   = (const float*)d_in[1];
    const float* mask   = (const float*)d_in[2];
    const float* rpbt   = (const float*)d_in[3];
    const float* q_w    = (const float*)d_in[4];
    const float* q_b    = (const float*)d_in[5];
    const float* kv_w   = (const float*)d_in[6];
    const float* kv_b   = (const float*)d_in[7];
    const float* pos    = (const float*)d_in[8];
    const float* pq_w   = (const float*)d_in[9];
    const float* pq_b   = (const float*)d_in[10];
    const float* pk_w   = (const float*)d_in[11];
    const float* pk_b   = (const float*)d_in[12];
    const float* pv_w   = (const float*)d_in[13];
    const float* pv_b   = (const float*)d_in[14];
    const float* po_w   = (const float*)d_in[15];
    const float* po_b   = (const float*)d_in[16];
    const float* proj_w = (const float*)d_in[17];
    const float* proj_b = (const float*)d_in[18];
    float* out = (float*)d_out;
    char* ws = (char*)d_ws;

    float*          qbuf   = (float*)(ws);                        // 24 MB
    unsigned short* xp     = (unsigned short*)(ws + 25165824u);   // 48 MB
    unsigned short* kbuf   = (unsigned short*)(ws + 75497472u);   // 12 MB
    unsigned short* vbuf   = (unsigned short*)(ws + 88080384u);   // 12 MB
    unsigned short* kkc    = (unsigned short*)(ws + 75497472u);   // 30 MB/chunk
    unsigned short* vvc    = (unsigned short*)(ws + 106954752u);  // 30 MB/chunk
    unsigned short* t0b    = (unsigned short*)(ws + 138412032u);  // 12.6 MB
    unsigned short* opoolb = (unsigned short*)(ws + 150994944u);  // 12.6 MB
    unsigned short* opob   = (unsigned short*)(ws + 163577856u);  // 12.6 MB
    unsigned short* wbf    = (unsigned short*)(ws + 176160768u);  // 0.59 MB
    float*          qq     = qbuf;

    dim3 blk(256);
    wcvt_kernel<<<1152, blk, 0, stream>>>(q_w, kv_w, pq_w, pk_w, pv_w, po_w, proj_w, wbf);
    // q = x @ q_w^T + q_b  (f32 A path)
    mgemm_kernel<0, 0, 0><<<dim3(256, 2), blk, 0, stream>>>(
        x, nullptr, nullptr, wbf, nullptr, q_b, nullptr, qbuf, nullptr, 0);
    // k,v = x_kv @ kv_w^T + kv_b  (split, bf16 out)
    mgemm_kernel<0, 2, 1><<<dim3(256, 4), blk, 0, stream>>>(
        x_kv, nullptr, nullptr, wbf + 36864, nullptr, kv_b, nullptr, kbuf, vbuf, 0);
    winattn_kernel<<<2048, 768, 0, stream>>>(qbuf, kbuf, vbuf, mask, rpbt, xp);
    // xp += pos (in place); t0 = mean_m(xp) + pos
    prep_kernel<<<3072, blk, 0, stream>>>(xp, pos, t0b);
    // qq = t0 @ pq_w^T + pq_b  (pure-copy A)
    mgemm_kernel<3, 0, 0><<<dim3(256, 2), blk, 0, stream>>>(
        nullptr, t0b, nullptr, wbf + 110592, nullptr, pq_b, nullptr, qq, nullptr, 0);
    // pooling in 2 chunks of 256 bt
    for (int c0 = 0; c0 < 512; c0 += 256) {
        mgemm_kernel<4, 3, 1><<<dim3(640, 4), blk, 0, stream>>>(
            nullptr, xp, t0b, wbf + 147456, wbf + 184320, pk_b, pv_b, kkc, vvc, c0);
        poolattn3_kernel<<<dim3(6, 256), 320, 0, stream>>>(kkc, vvc, qq, opoolb, c0);
    }
    // opo = gelu(opool @ po_w^T + po_b)  (bf16 in/out)
    mgemm_kernel<3, 1, 1><<<dim3(256, 2), blk, 0, stream>>>(
        nullptr, opoolb, nullptr, wbf + 221184, nullptr, po_b, nullptr, opob, nullptr, 0);
    // out = opo @ proj_w^T + proj_b  (f32 out)
    mgemm_kernel<3, 0, 0><<<dim3(256, 2), blk, 0, stream>>>(
        nullptr, opob, nullptr, wbf + 258048, nullptr, proj_b, nullptr, out, nullptr, 0);
}

// Round 15
// 626.334 us; speedup vs baseline: 2.0752x; 1.0431x over previous
//
#include <hip/hip_runtime.h>
#include <math.h>

// ---------------------------------------------------------------------------
// MultiReferenceWindowAttention — bf16-MFMA GEMMs (pure-copy staging,
// coalesced bf16 epilogue) + t-merged window attention.
// B_=128, T=4, M=4, N=64, C=192, nH=6, hd=32, BT=512
// Workspace (<= proven 177,340,416 B): same map as r14, peak 176.75 MB.
//
// VGPR/SPILL MODEL (r7..r13, settled): hipcc targets ~84 VGPR for 768-thread
// blocks and SPILLS rather than exceed it. winattn's f32-LDS core fits at 80
// (zero spill); bf16-unpack variants need ~96+ -> 1.7-2.9 GB scratch. KEEP
// the f32 core; all per-t state transient.
// r14 lesson: GEMM staging cvt was 2x MFMA time -> pure-copy staging.
// r15: t-merge winattn staging (4x reuse), pos folded into winattn epilogue,
// LDS-staged coalesced bf16 GEMM epilogue (48 scalar 2B stores -> 6 u16x8).
// ---------------------------------------------------------------------------

typedef float f32x4 __attribute__((ext_vector_type(4)));
typedef short s16x8 __attribute__((ext_vector_type(8)));
typedef unsigned short u16x4 __attribute__((ext_vector_type(4)));
typedef unsigned short u16x8 __attribute__((ext_vector_type(8)));

__device__ __forceinline__ unsigned short f2bf(float f) {
    union { float f; unsigned u; } c; c.f = f;
    return (unsigned short)((c.u + 0x7fffu + ((c.u >> 16) & 1u)) >> 16);
}
__device__ __forceinline__ float bf2f(unsigned short h) {
    union { unsigned u; float f; } c; c.u = ((unsigned)h) << 16;
    return c.f;
}

// ---- all 7 weights -> packed bf16 (element offsets: q 0, kv 36864,
// pq 110592, pk 147456, pv 184320, po 221184, proj 258048; total 294912)
__global__ void wcvt_kernel(const float* __restrict__ q_w, const float* __restrict__ kv_w,
                            const float* __restrict__ pq_w, const float* __restrict__ pk_w,
                            const float* __restrict__ pv_w, const float* __restrict__ po_w,
                            const float* __restrict__ proj_w, unsigned short* __restrict__ wbf)
{
    int i = blockIdx.x * 256 + threadIdx.x;
    if (i >= 294912) return;
    const float* src; int off;
    if      (i < 36864)  { src = q_w;    off = 0; }
    else if (i < 110592) { src = kv_w;   off = 36864; }
    else if (i < 147456) { src = pq_w;   off = 110592; }
    else if (i < 184320) { src = pk_w;   off = 147456; }
    else if (i < 221184) { src = pv_w;   off = 184320; }
    else if (i < 258048) { src = po_w;   off = 221184; }
    else                 { src = proj_w; off = 258048; }
    wbf[i] = f2bf(src[i - off]);
}

// ---- prep: t0b = mean_m(xp2)  (xp2 already includes pos, added in winattn)
__global__ void prep_kernel(const unsigned short* __restrict__ xp,
                            unsigned short* __restrict__ t0b)
{
    int i = blockIdx.x * 256 + threadIdx.x;   // 786432 total
    int c8 = (i % 24) * 8;
    int n  = (i / 24) & 63;
    int bt = i / (24 * 64);
    float acc[8] = {0, 0, 0, 0, 0, 0, 0, 0};
    size_t base = (size_t)bt * 49152 + n * 192 + c8;
#pragma unroll
    for (int m = 0; m < 4; m++) {
        u16x8 v = *reinterpret_cast<const u16x8*>(&xp[base + m * 12288]);
#pragma unroll
        for (int e = 0; e < 8; e++) acc[e] += bf2f(v[e]);
    }
    u16x8 t;
#pragma unroll
    for (int e = 0; e < 8; e++) t[e] = f2bf(acc[e] * 0.25f);
    *reinterpret_cast<u16x8*>(&t0b[(size_t)(bt * 64 + n) * 192 + c8]) = t;
}

// ---------------------------------------------------------------------------
// MFMA bf16 GEMM:  C[row, oc] = sum_k Arow[k] * W[oc][k] + bias[oc]
// Block tile 128 rows x 96 oc, K=192 staged in 2 halves of 96. Weights bf16.
// SRC: 0 = A f32 rows (cvt); 3 = Ab bf16 row-major (pure copy);
//      4 = seq rows: g -> (bt=c0+g/320, tok); tok<64 -> Ab2(t0b) else Ab(xp2).
// EPI: 0 plain, 1 exact gelu, 2 split oc@192 (b0 len 384), 3 split (W1,b1).
// OUTBF: 0 f32 out (64B/16-lane stores, fine); 1 bf16 out via LDS restage
//        -> 6 coalesced u16x8 stores per thread.
// ---------------------------------------------------------------------------
template <int SRC, int EPI, int OUTBF>
__global__ __launch_bounds__(256, 3)
void mgemm_kernel(const float* __restrict__ A, const unsigned short* __restrict__ Ab,
                  const unsigned short* __restrict__ Ab2,
                  const unsigned short* __restrict__ W0, const unsigned short* __restrict__ W1,
                  const float* __restrict__ b0, const float* __restrict__ b1,
                  void* __restrict__ C0v, void* __restrict__ C1v, int c0)
{
    __shared__ __align__(16) char As[128 * 192];   // 24 KB bf16 [row][k(96)]
    __shared__ __align__(16) char Bs[96 * 192];    // 18 KB bf16 [oc][k(96)]
    const int tid = threadIdx.x;
    const int gm0 = blockIdx.x * 128;
    const int gn0 = blockIdx.y * 96;
    const int wid = tid >> 6;
    const int wm = wid >> 1, wn = wid & 1;
    const int lane = tid & 63;
    const int lr = lane & 15;
    const int lk = lane >> 4;

    const bool hiN = (gn0 >= 192);
    const unsigned short* Wsel = (EPI == 3 && hiN) ? W1 : W0;
    const int wrow0 = (EPI == 3 && hiN) ? (gn0 - 192) : gn0;

    f32x4 acc[4][3];
#pragma unroll
    for (int i = 0; i < 4; i++)
#pragma unroll
        for (int j = 0; j < 3; j++) acc[i][j] = (f32x4){0.f, 0.f, 0.f, 0.f};

    for (int kb = 0; kb < 192; kb += 96) {
        // ---- stage A ----
        if (SRC == 0) {
#pragma unroll
            for (int it = 0; it < 12; it++) {
                int f4 = tid + it * 256;
                int row = f4 / 24;
                int kc4 = (f4 - row * 24) * 4;
                float4 v = *reinterpret_cast<const float4*>(
                    &A[(size_t)(gm0 + row) * 192 + kb + kc4]);
                u16x4 bvv;
                bvv[0] = f2bf(v.x); bvv[1] = f2bf(v.y);
                bvv[2] = f2bf(v.z); bvv[3] = f2bf(v.w);
                int boff = (kc4 * 2) ^ ((row & 3) << 4);
                *reinterpret_cast<u16x4*>(As + row * 192 + boff) = bvv;
            }
        } else {
#pragma unroll
            for (int it = 0; it < 6; it++) {
                int f8 = tid + it * 256;
                int row = f8 / 12;
                int c16 = f8 - row * 12;
                const unsigned short* src;
                if (SRC == 3) {
                    src = &Ab[(size_t)(gm0 + row) * 192 + kb + c16 * 8];
                } else {
                    int g = gm0 + row;
                    int bt = g / 320, tok = g - bt * 320; bt += c0;
                    src = (tok < 64)
                        ? &Ab2[(size_t)(bt * 64 + tok) * 192 + kb + c16 * 8]
                        : &Ab[(size_t)bt * 49152 + ((tok >> 6) - 1) * 12288
                              + (tok & 63) * 192 + kb + c16 * 8];
                }
                u16x8 v = *reinterpret_cast<const u16x8*>(src);
                int boff = (c16 * 16) ^ ((row & 3) << 4);
                *reinterpret_cast<u16x8*>(As + row * 192 + boff) = v;
            }
        }
        // ---- stage B: 96 oc-rows x 96 k, pure bf16 copy ----
        for (int f8 = tid; f8 < 1152; f8 += 256) {
            int row = f8 / 12;
            int c16 = f8 - row * 12;
            u16x8 v = *reinterpret_cast<const u16x8*>(
                &Wsel[(size_t)(wrow0 + row) * 192 + kb + c16 * 8]);
            int boff = (c16 * 16) ^ ((row & 3) << 4);
            *reinterpret_cast<u16x8*>(Bs + row * 192 + boff) = v;
        }
        __syncthreads();

#pragma unroll
        for (int ks = 0; ks < 3; ks++) {
            s16x8 af[4], bf[3];
#pragma unroll
            for (int i = 0; i < 4; i++) {
                int row = wm * 64 + i * 16 + lr;
                int off = (ks * 64 + lk * 16) ^ ((row & 3) << 4);
                af[i] = *reinterpret_cast<const s16x8*>(As + row * 192 + off);
            }
#pragma unroll
            for (int j = 0; j < 3; j++) {
                int row = wn * 48 + j * 16 + lr;
                int off = (ks * 64 + lk * 16) ^ ((row & 3) << 4);
                bf[j] = *reinterpret_cast<const s16x8*>(Bs + row * 192 + off);
            }
#pragma unroll
            for (int i = 0; i < 4; i++)
#pragma unroll
                for (int j = 0; j < 3; j++)
                    acc[i][j] = __builtin_amdgcn_mfma_f32_16x16x32_bf16(
                        af[i], bf[j], acc[i][j], 0, 0, 0);
        }
        __syncthreads();
    }

    if (OUTBF == 0) {
        // f32 out: 16 lanes x 4B = full 64B line, direct stores are coalesced
#pragma unroll
        for (int j = 0; j < 3; j++) {
            int bcol = gn0 + wn * 48 + j * 16 + lr;
            float bv = (EPI == 3 && bcol >= 192) ? b1[bcol - 192] : b0[bcol];
            float* dst = (float*)C0v;
            int oc = bcol;
            if ((EPI == 2 || EPI == 3) && bcol >= 192) { dst = (float*)C1v; oc = bcol - 192; }
#pragma unroll
            for (int i = 0; i < 4; i++) {
                int rbase = gm0 + wm * 64 + i * 16 + lk * 4;
#pragma unroll
                for (int r = 0; r < 4; r++) {
                    float v = acc[i][j][r] + bv;
                    if (EPI == 1) v = 0.5f * v * (1.f + erff(v * 0.70710678118654752440f));
                    dst[(size_t)(rbase + r) * 192 + oc] = v;
                }
            }
        }
    } else {
        // bf16 out: restage via As (exactly 128*96 u16 = 24 KB), then
        // 6 coalesced u16x8 stores per thread.
        unsigned short* As16 = (unsigned short*)As;
#pragma unroll
        for (int j = 0; j < 3; j++) {
            int bcol = gn0 + wn * 48 + j * 16 + lr;
            float bv = (EPI == 3 && bcol >= 192) ? b1[bcol - 192] : b0[bcol];
#pragma unroll
            for (int i = 0; i < 4; i++)
#pragma unroll
                for (int r = 0; r < 4; r++) {
                    float v = acc[i][j][r] + bv;
                    if (EPI == 1) v = 0.5f * v * (1.f + erff(v * 0.70710678118654752440f));
                    As16[(wm * 64 + i * 16 + lk * 4 + r) * 96 + wn * 48 + j * 16 + lr] = f2bf(v);
                }
        }
        __syncthreads();
        unsigned short* dst = (unsigned short*)((((EPI == 2) || (EPI == 3)) && hiN) ? C1v : C0v);
        const int oc0 = ((((EPI == 2) || (EPI == 3)) && hiN) ? gn0 - 192 : gn0);
#pragma unroll
        for (int it = 0; it < 6; it++) {
            int f8 = tid + it * 256;
            int row = f8 / 12, c16 = f8 - row * 12;
            u16x8 v = *reinterpret_cast<const u16x8*>(&As16[row * 96 + c16 * 8]);
            *reinterpret_cast<u16x8*>(&dst[(size_t)(gm0 + row) * 192 + oc0 + c16 * 8]) = v;
        }
    }
}

// ---------------------------------------------------------------------------
// Fused window attention, t-MERGED (r15): block = (bb, m), 512 blocks,
// 768 thr = 12 waves. K/V/mask/rpbT staged F32 in LDS ONCE, then t=0..3
// looped inside (per-t state fully transient -> VGPR stays ~80, no spill).
// Wave w: head h = w>>1, keys [(w&1)*32 .. +32); pair-merge via LDS.
// Epilogue adds pos (scrambled-layout flat index) before bf16 rounding.
// ---------------------------------------------------------------------------
__global__ __launch_bounds__(768, 1)
void winattn_kernel(const float* __restrict__ qbuf,
                    const unsigned short* __restrict__ kbuf,
                    const unsigned short* __restrict__ vbuf,
                    const float* __restrict__ mask,
                    const float* __restrict__ rpbt, const float* __restrict__ pos,
                    unsigned short* __restrict__ xp)
{
    __shared__ float klds[64 * 192];       // 48 KB
    __shared__ float vlds[64 * 192];       // 48 KB
    __shared__ float mlds[64 * 65];        // 16.25 KB
    __shared__ float rldsT[6 * 225];       // 5.3 KB  [h][ridx]
    __shared__ float exm[768];
    __shared__ float exl[768];
    __shared__ unsigned obuf[6 * 64 * 17]; // 25.5 KB
    const int tid = threadIdx.x;
    const int bid = blockIdx.x;            // bb*4 + m
    const int bb = bid >> 2;
    const int m = bid & 3;
    const int w = tid >> 6;
    const int h = w >> 1;
    const int lane = tid & 63;

    const int kvbase = (bb * 4 + m) * 12288;
#pragma unroll
    for (int it = 0; it < 2; it++) {
        int i8 = tid + it * 768;
        u16x8 kq = *reinterpret_cast<const u16x8*>(&kbuf[kvbase + i8 * 8]);
        u16x8 vq = *reinterpret_cast<const u16x8*>(&vbuf[kvbase + i8 * 8]);
        f32x4 k0, k1, v0, v1;
#pragma unroll
        for (int e = 0; e < 4; e++) {
            k0[e] = bf2f(kq[e]); k1[e] = bf2f(kq[e + 4]);
            v0[e] = bf2f(vq[e]); v1[e] = bf2f(vq[e + 4]);
        }
        *reinterpret_cast<f32x4*>(&klds[i8 * 8]) = k0;
        *reinterpret_cast<f32x4*>(&klds[i8 * 8 + 4]) = k1;
        *reinterpret_cast<f32x4*>(&vlds[i8 * 8]) = v0;
        *reinterpret_cast<f32x4*>(&vlds[i8 * 8 + 4]) = v1;
    }
    const int widx = bb & 63;
    for (int f = tid; f < 4096; f += 768)
        mlds[(f >> 6) * 65 + (f & 63)] = mask[widx * 4096 + f];
    for (int f = tid; f < 1350; f += 768) {
        int hh = f / 225, rr = f - hh * 225;
        rldsT[f] = rpbt[rr * 6 + hh];
    }
    __syncthreads();

    const float scale = 0.17677669529663688110f;  // 1/sqrt(32)
    const int ni = lane >> 3, nj = lane & 7;
    const int e0 = (w & 1) << 5;

    for (int t = 0; t < 4; t++) {
        float qreg[32];
        const int qbase = ((bb * 4 + t) * 64 + lane) * 192 + h * 32;
#pragma unroll
        for (int j = 0; j < 8; j++) {
            float4 v = *reinterpret_cast<const float4*>(&qbuf[qbase + j * 4]);
            qreg[4 * j] = v.x; qreg[4 * j + 1] = v.y;
            qreg[4 * j + 2] = v.z; qreg[4 * j + 3] = v.w;
        }
        float s[32];
#pragma unroll
        for (int ee = 0; ee < 32; ee++) {
            int e = e0 + ee;
            const float4* kr = reinterpret_cast<const float4*>(&klds[e * 192 + h * 32]);
            float d0 = 0, d1 = 0, d2 = 0, d3 = 0;
#pragma unroll
            for (int q8 = 0; q8 < 8; q8++) {
                float4 k4 = kr[q8];
                d0 += qreg[q8 * 4] * k4.x;
                d1 += qreg[q8 * 4 + 1] * k4.y;
                d2 += qreg[q8 * 4 + 2] * k4.z;
                d3 += qreg[q8 * 4 + 3] * k4.w;
            }
            int ridx = (ni - (e >> 3) + 7) * 15 + (nj - (e & 7) + 7);
            s[ee] = (d0 + d1 + d2 + d3) * scale + rldsT[h * 225 + ridx] + mlds[lane * 65 + e];
        }
        float mrun = s[0];
#pragma unroll
        for (int ee = 1; ee < 32; ee++) mrun = fmaxf(mrun, s[ee]);
        float lrun = 0.f;
#pragma unroll
        for (int ee = 0; ee < 32; ee++) { s[ee] = __expf(s[ee] - mrun); lrun += s[ee]; }

        float o[32];
#pragma unroll
        for (int d = 0; d < 32; d++) o[d] = 0.f;
#pragma unroll
        for (int ee = 0; ee < 32; ee++) {
            float p = s[ee];
            const float4* vr = reinterpret_cast<const float4*>(&vlds[(e0 + ee) * 192 + h * 32]);
#pragma unroll
            for (int d8 = 0; d8 < 8; d8++) {
                float4 v4 = vr[d8];
                o[d8 * 4] += p * v4.x; o[d8 * 4 + 1] += p * v4.y;
                o[d8 * 4 + 2] += p * v4.z; o[d8 * 4 + 3] += p * v4.w;
            }
        }

        // ---- pair merge (exm/exl/obuf are per-t scratch; B1 guards reuse) ----
        __syncthreads();                   // B1: prior t's obuf/exl reads done
        exm[w * 64 + lane] = mrun;
        __syncthreads();                   // B2
        float mo = exm[(w ^ 1) * 64 + lane];
        float mt = fmaxf(mrun, mo);
        float fs = __expf(mrun - mt);
        if (w & 1) {
            unsigned* ob = &obuf[h * 1088 + lane * 17];
#pragma unroll
            for (int j = 0; j < 16; j++) {
                unsigned lo = f2bf(fs * o[2 * j]);
                unsigned hi = f2bf(fs * o[2 * j + 1]);
                ob[j] = lo | (hi << 16);
            }
            exl[w * 64 + lane] = fs * lrun;
        }
        __syncthreads();                   // B3
        if (!(w & 1)) {
            float lt = fs * lrun + exl[(w + 1) * 64 + lane];
            const float inv = 1.f / lt;
            const unsigned* ob = &obuf[h * 1088 + lane * 17];
            const int obase = bb * 196608 + m * 49152 + t * 12288 + h * 2048 + lane * 32;
#pragma unroll
            for (int j = 0; j < 8; j++) {
                unsigned p0 = ob[2 * j], p1 = ob[2 * j + 1];
                float4 pv = *reinterpret_cast<const float4*>(&pos[h * 2048 + lane * 32 + j * 4]);
                u16x4 v;
                v[0] = f2bf((fs * o[4 * j]     + bf2f((unsigned short)(p0 & 0xffff))) * inv + pv.x);
                v[1] = f2bf((fs * o[4 * j + 1] + bf2f((unsigned short)(p0 >> 16))) * inv + pv.y);
                v[2] = f2bf((fs * o[4 * j + 2] + bf2f((unsigned short)(p1 & 0xffff))) * inv + pv.z);
                v[3] = f2bf((fs * o[4 * j + 3] + bf2f((unsigned short)(p1 >> 16))) * inv + pv.w);
                *reinterpret_cast<u16x4*>(&xp[obase + j * 4]) = v;
            }
        }
    }
}

// ---------------------------------------------------------------------------
// Pooling attention (r7 known-good f32-LDS core; bf16 out):
// block = (h, btl), 320 threads = 5 waves; wave w handles key tiles {w, w+5}.
// ---------------------------------------------------------------------------
__global__ __launch_bounds__(320)
void poolattn3_kernel(const unsigned short* __restrict__ kk,
                      const unsigned short* __restrict__ vv,
                      const float* __restrict__ qq,
                      unsigned short* __restrict__ opool, int c0)
{
    __shared__ float ubuf[10560];
    __shared__ float scm[320], scl[320];
    const int tid = threadIdx.x;
    const int w = tid >> 6, lane = tid & 63;
    const int h = blockIdx.x, btl = blockIdx.y;
    const int bt = c0 + btl;
    float* Kf = ubuf + w * 2048;
    float* Vf = Kf + 1024;

    float qreg[32];
    const size_t qbase = (size_t)(bt * 64 + lane) * 192 + h * 32;
#pragma unroll
    for (int j = 0; j < 8; j++) {
        float4 v = *reinterpret_cast<const float4*>(&qq[qbase + j * 4]);
        qreg[4 * j] = v.x; qreg[4 * j + 1] = v.y;
        qreg[4 * j + 2] = v.z; qreg[4 * j + 3] = v.w;
    }
    const float scale = 0.17677669529663688110f;
    float mrun = -3.0e38f, lrun = 0.f;
    float o[32];
#pragma unroll
    for (int d = 0; d < 32; d++) o[d] = 0.f;

#pragma unroll
    for (int it = 0; it < 2; it++) {
        const int tt = w + it * 5;
        const unsigned short* ks = kk + (size_t)(btl * 320 + tt * 32) * 192 + h * 32;
        const unsigned short* vs = vv + (size_t)(btl * 320 + tt * 32) * 192 + h * 32;
#pragma unroll
        for (int ci = 0; ci < 2; ci++) {
            int idx = lane + ci * 64;
            int j = idx >> 2, q4 = (idx & 3) * 8;
            s16x8 kv8 = *reinterpret_cast<const s16x8*>(&ks[j * 192 + q4]);
            s16x8 vv8 = *reinterpret_cast<const s16x8*>(&vs[j * 192 + q4]);
            f32x4 lo, hi, vlo, vhi;
#pragma unroll
            for (int e = 0; e < 4; e++) {
                lo[e] = bf2f((unsigned short)kv8[e]);
                hi[e] = bf2f((unsigned short)kv8[e + 4]);
                vlo[e] = bf2f((unsigned short)vv8[e]);
                vhi[e] = bf2f((unsigned short)vv8[e + 4]);
            }
            *reinterpret_cast<f32x4*>(Kf + j * 32 + q4) = lo;
            *reinterpret_cast<f32x4*>(Kf + j * 32 + q4 + 4) = hi;
            *reinterpret_cast<f32x4*>(Vf + j * 32 + q4) = vlo;
            *reinterpret_cast<f32x4*>(Vf + j * 32 + q4 + 4) = vhi;
        }
        float s[32];
#pragma unroll
        for (int j = 0; j < 32; j++) {
            const float4* kr = reinterpret_cast<const float4*>(Kf + j * 32);
            float d0 = 0, d1 = 0, d2 = 0, d3 = 0;
#pragma unroll
            for (int q8 = 0; q8 < 8; q8++) {
                float4 k4 = kr[q8];
                d0 += qreg[q8 * 4] * k4.x;
                d1 += qreg[q8 * 4 + 1] * k4.y;
                d2 += qreg[q8 * 4 + 2] * k4.z;
                d3 += qreg[q8 * 4 + 3] * k4.w;
            }
            s[j] = (d0 + d1 + d2 + d3) * scale;
        }
        float mt = s[0];
#pragma unroll
        for (int j = 1; j < 32; j++) mt = fmaxf(mt, s[j]);
        float mnew = fmaxf(mrun, mt);
        float fct = __expf(mrun - mnew);
        lrun *= fct;
#pragma unroll
        for (int d = 0; d < 32; d++) o[d] *= fct;
#pragma unroll
        for (int j = 0; j < 32; j++) { float p = __expf(s[j] - mnew); lrun += p; s[j] = p; }
#pragma unroll
        for (int j = 0; j < 32; j++) {
            float p = s[j];
            const float4* vr = reinterpret_cast<const float4*>(Vf + j * 32);
#pragma unroll
            for (int d8 = 0; d8 < 8; d8++) {
                float4 v4 = vr[d8];
                o[d8 * 4] += p * v4.x; o[d8 * 4 + 1] += p * v4.y;
                o[d8 * 4 + 2] += p * v4.z; o[d8 * 4 + 3] += p * v4.w;
            }
        }
        mrun = mnew;
    }
    __syncthreads();
    scm[w * 64 + lane] = mrun;
    scl[w * 64 + lane] = lrun;
#pragma unroll
    for (int d = 0; d < 32; d++) ubuf[w * 2112 + lane * 33 + d] = o[d];
    __syncthreads();

    if (w == 0) {
        float m5 = scm[lane];
#pragma unroll
        for (int ww = 1; ww < 5; ww++) m5 = fmaxf(m5, scm[ww * 64 + lane]);
        float den = 0.f;
        float od[32];
#pragma unroll
        for (int d = 0; d < 32; d++) od[d] = 0.f;
#pragma unroll
        for (int ww = 0; ww < 5; ww++) {
            float f = __expf(scm[ww * 64 + lane] - m5);
            den += f * scl[ww * 64 + lane];
            const float* src = ubuf + ww * 2112 + lane * 33;
#pragma unroll
            for (int d = 0; d < 32; d++) od[d] += f * src[d];
        }
        const float inv = 1.f / den;
        const size_t ob = (size_t)(bt * 64 + lane) * 192 + h * 32;
#pragma unroll
        for (int j = 0; j < 8; j++) {
            u16x4 v;
            v[0] = f2bf(od[4 * j] * inv);     v[1] = f2bf(od[4 * j + 1] * inv);
            v[2] = f2bf(od[4 * j + 2] * inv); v[3] = f2bf(od[4 * j + 3] * inv);
            *reinterpret_cast<u16x4*>(&opool[ob + j * 4]) = v;
        }
    }
}

extern "C" void kernel_launch(void* const* d_in, const int* in_sizes, int n_in,
                              void* d_out, int out_size, void* d_ws, size_t ws_size,
                              hipStream_t stream) {
    (void)in_sizes; (void)n_in; (void)out_size; (void)ws_size;
    const float* x      = (const float*)d_in[0];
    const float* x_kv   = (const float*)d_in[1];
    const float* mask   = (const float*)d_in[2];
    const float* rpbt   = (const float*)d_in[3];
    const float* q_w    = (const float*)d_in[4];
    const float* q_b    = (const float*)d_in[5];
    const float* kv_w   = (const float*)d_in[6];
    const float* kv_b   = (const float*)d_in[7];
    const float* pos    = (const float*)d_in[8];
    const float* pq_w   = (const float*)d_in[9];
    const float* pq_b   = (const float*)d_in[10];
    const float* pk_w   = (const float*)d_in[11];
    const float* pk_b   = (const float*)d_in[12];
    const float* pv_w   = (const float*)d_in[13];
    const float* pv_b   = (const float*)d_in[14];
    const float* po_w   = (const float*)d_in[15];
    const float* po_b   = (const float*)d_in[16];
    const float* proj_w = (const float*)d_in[17];
    const float* proj_b = (const float*)d_in[18];
    float* out = (float*)d_out;
    char* ws = (char*)d_ws;

    float*          qbuf   = (float*)(ws);                        // 24 MB
    unsigned short* xp     = (unsigned short*)(ws + 25165824u);   // 48 MB
    unsigned short* kbuf   = (unsigned short*)(ws + 75497472u);   // 12 MB
    unsigned short* vbuf   = (unsigned short*)(ws + 88080384u);   // 12 MB
    unsigned short* kkc    = (unsigned short*)(ws + 75497472u);   // 30 MB/chunk
    unsigned short* vvc    = (unsigned short*)(ws + 106954752u);  // 30 MB/chunk
    unsigned short* t0b    = (unsigned short*)(ws + 138412032u);  // 12.6 MB
    unsigned short* opoolb = (unsigned short*)(ws + 150994944u);  // 12.6 MB
    unsigned short* opob   = (unsigned short*)(ws + 163577856u);  // 12.6 MB
    unsigned short* wbf    = (unsigned short*)(ws + 176160768u);  // 0.59 MB
    float*          qq     = qbuf;

    dim3 blk(256);
    wcvt_kernel<<<1152, blk, 0, stream>>>(q_w, kv_w, pq_w, pk_w, pv_w, po_w, proj_w, wbf);
    // q = x @ q_w^T + q_b  (f32 A path)
    mgemm_kernel<0, 0, 0><<<dim3(256, 2), blk, 0, stream>>>(
        x, nullptr, nullptr, wbf, nullptr, q_b, nullptr, qbuf, nullptr, 0);
    // k,v = x_kv @ kv_w^T + kv_b  (split, bf16 out, coalesced epilogue)
    mgemm_kernel<0, 2, 1><<<dim3(256, 4), blk, 0, stream>>>(
        x_kv, nullptr, nullptr, wbf + 36864, nullptr, kv_b, nullptr, kbuf, vbuf, 0);
    // window attention, t-merged; writes xp2 = attn_out + pos
    winattn_kernel<<<512, 768, 0, stream>>>(qbuf, kbuf, vbuf, mask, rpbt, pos, xp);
    // t0 = mean_m(xp2)
    prep_kernel<<<3072, blk, 0, stream>>>(xp, t0b);
    // qq = t0 @ pq_w^T + pq_b
    mgemm_kernel<3, 0, 0><<<dim3(256, 2), blk, 0, stream>>>(
        nullptr, t0b, nullptr, wbf + 110592, nullptr, pq_b, nullptr, qq, nullptr, 0);
    // pooling in 2 chunks of 256 bt
    for (int c0 = 0; c0 < 512; c0 += 256) {
        mgemm_kernel<4, 3, 1><<<dim3(640, 4), blk, 0, stream>>>(
            nullptr, xp, t0b, wbf + 147456, wbf + 184320, pk_b, pv_b, kkc, vvc, c0);
        poolattn3_kernel<<<dim3(6, 256), 320, 0, stream>>>(kkc, vvc, qq, opoolb, c0);
    }
    // opo = gelu(opool @ po_w^T + po_b)  (bf16 in/out)
    mgemm_kernel<3, 1, 1><<<dim3(256, 2), blk, 0, stream>>>(
        nullptr, opoolb, nullptr, wbf + 221184, nullptr, po_b, nullptr, opob, nullptr, 0);
    // out = opo @ proj_w^T + proj_b  (f32 out)
    mgemm_kernel<3, 0, 0><<<dim3(256, 2), blk, 0, stream>>>(
        nullptr, opob, nullptr, wbf + 258048, nullptr, proj_b, nullptr, out, nullptr, 0);
}

// Round 16
// 600.867 us; speedup vs baseline: 2.1632x; 1.0424x over previous
//
#include <hip/hip_runtime.h>
#include <math.h>

// ---------------------------------------------------------------------------
// MultiReferenceWindowAttention — bf16-MFMA GEMMs (pure-copy staging,
// coalesced bf16 epilogue, head-blocked kk/vv) + t-merged window attention.
// B_=128, T=4, M=4, N=64, C=192, nH=6, hd=32, BT=512
// Workspace map unchanged from r14/r15, peak 176.75 MB (<= 177,340,416 B).
//
// VGPR/SPILL MODEL (settled r7..r15): hipcc targets ~84 VGPR for 768-thread
// blocks (and similar for 320-thread) and SPILLS rather than exceed. The rule
// is LIVE STATE <= ~84: winattn t-loop keeps per-t state transient (84, no
// spill). r16: poolattn3 had qreg[32] live ACROSS its key-tile loop
// (qreg+s+o ~ 96) -> reload qreg per iteration (#pragma unroll 1 defeats
// CSE-hoisting) so cross-phase live ~ 40.
// winattn is DS-pipe-bound (8 ds_read_b128 : 32 FMA per key) — parked.
// ---------------------------------------------------------------------------

typedef float f32x4 __attribute__((ext_vector_type(4)));
typedef short s16x8 __attribute__((ext_vector_type(8)));
typedef unsigned short u16x4 __attribute__((ext_vector_type(4)));
typedef unsigned short u16x8 __attribute__((ext_vector_type(8)));

__device__ __forceinline__ unsigned short f2bf(float f) {
    union { float f; unsigned u; } c; c.f = f;
    return (unsigned short)((c.u + 0x7fffu + ((c.u >> 16) & 1u)) >> 16);
}
__device__ __forceinline__ float bf2f(unsigned short h) {
    union { unsigned u; float f; } c; c.u = ((unsigned)h) << 16;
    return c.f;
}

// ---- all 7 weights -> packed bf16 (element offsets: q 0, kv 36864,
// pq 110592, pk 147456, pv 184320, po 221184, proj 258048; total 294912)
__global__ void wcvt_kernel(const float* __restrict__ q_w, const float* __restrict__ kv_w,
                            const float* __restrict__ pq_w, const float* __restrict__ pk_w,
                            const float* __restrict__ pv_w, const float* __restrict__ po_w,
                            const float* __restrict__ proj_w, unsigned short* __restrict__ wbf)
{
    int i = blockIdx.x * 256 + threadIdx.x;
    if (i >= 294912) return;
    const float* src; int off;
    if      (i < 36864)  { src = q_w;    off = 0; }
    else if (i < 110592) { src = kv_w;   off = 36864; }
    else if (i < 147456) { src = pq_w;   off = 110592; }
    else if (i < 184320) { src = pk_w;   off = 147456; }
    else if (i < 221184) { src = pv_w;   off = 184320; }
    else if (i < 258048) { src = po_w;   off = 221184; }
    else                 { src = proj_w; off = 258048; }
    wbf[i] = f2bf(src[i - off]);
}

// ---- prep: t0b = mean_m(xp2)  (xp2 already includes pos, added in winattn)
__global__ void prep_kernel(const unsigned short* __restrict__ xp,
                            unsigned short* __restrict__ t0b)
{
    int i = blockIdx.x * 256 + threadIdx.x;   // 786432 total
    int c8 = (i % 24) * 8;
    int n  = (i / 24) & 63;
    int bt = i / (24 * 64);
    float acc[8] = {0, 0, 0, 0, 0, 0, 0, 0};
    size_t base = (size_t)bt * 49152 + n * 192 + c8;
#pragma unroll
    for (int m = 0; m < 4; m++) {
        u16x8 v = *reinterpret_cast<const u16x8*>(&xp[base + m * 12288]);
#pragma unroll
        for (int e = 0; e < 8; e++) acc[e] += bf2f(v[e]);
    }
    u16x8 t;
#pragma unroll
    for (int e = 0; e < 8; e++) t[e] = f2bf(acc[e] * 0.25f);
    *reinterpret_cast<u16x8*>(&t0b[(size_t)(bt * 64 + n) * 192 + c8]) = t;
}

// ---------------------------------------------------------------------------
// MFMA bf16 GEMM:  C[row, oc] = sum_k Arow[k] * W[oc][k] + bias[oc]
// Block tile 128 rows x 96 oc, K=192 staged in 2 halves of 96. Weights bf16.
// SRC: 0 = A f32 rows (cvt); 3 = Ab bf16 row-major (pure copy);
//      4 = seq rows: g -> (bt=c0+g/320, tok); tok<64 -> Ab2(t0b) else Ab(xp2).
// EPI: 0 plain, 1 exact gelu, 2 split oc@192 (b0 len 384), 3 split (W1,b1).
// OUTBF: 0 f32 out; 1 bf16 out via LDS restage -> coalesced u16x8 stores.
// hbs: 0 = row-major [row][192] out; else head-blocked [h][row][32] with
//      h-stride = hbs elements (8-col store chunks never cross a head).
// ---------------------------------------------------------------------------
template <int SRC, int EPI, int OUTBF>
__global__ __launch_bounds__(256, 3)
void mgemm_kernel(const float* __restrict__ A, const unsigned short* __restrict__ Ab,
                  const unsigned short* __restrict__ Ab2,
                  const unsigned short* __restrict__ W0, const unsigned short* __restrict__ W1,
                  const float* __restrict__ b0, const float* __restrict__ b1,
                  void* __restrict__ C0v, void* __restrict__ C1v, int c0, int hbs)
{
    __shared__ __align__(16) char As[128 * 192];   // 24 KB bf16 [row][k(96)]
    __shared__ __align__(16) char Bs[96 * 192];    // 18 KB bf16 [oc][k(96)]
    const int tid = threadIdx.x;
    const int gm0 = blockIdx.x * 128;
    const int gn0 = blockIdx.y * 96;
    const int wid = tid >> 6;
    const int wm = wid >> 1, wn = wid & 1;
    const int lane = tid & 63;
    const int lr = lane & 15;
    const int lk = lane >> 4;

    const bool hiN = (gn0 >= 192);
    const unsigned short* Wsel = (EPI == 3 && hiN) ? W1 : W0;
    const int wrow0 = (EPI == 3 && hiN) ? (gn0 - 192) : gn0;

    f32x4 acc[4][3];
#pragma unroll
    for (int i = 0; i < 4; i++)
#pragma unroll
        for (int j = 0; j < 3; j++) acc[i][j] = (f32x4){0.f, 0.f, 0.f, 0.f};

    for (int kb = 0; kb < 192; kb += 96) {
        // ---- stage A ----
        if (SRC == 0) {
#pragma unroll
            for (int it = 0; it < 12; it++) {
                int f4 = tid + it * 256;
                int row = f4 / 24;
                int kc4 = (f4 - row * 24) * 4;
                float4 v = *reinterpret_cast<const float4*>(
                    &A[(size_t)(gm0 + row) * 192 + kb + kc4]);
                u16x4 bvv;
                bvv[0] = f2bf(v.x); bvv[1] = f2bf(v.y);
                bvv[2] = f2bf(v.z); bvv[3] = f2bf(v.w);
                int boff = (kc4 * 2) ^ ((row & 3) << 4);
                *reinterpret_cast<u16x4*>(As + row * 192 + boff) = bvv;
            }
        } else {
#pragma unroll
            for (int it = 0; it < 6; it++) {
                int f8 = tid + it * 256;
                int row = f8 / 12;
                int c16 = f8 - row * 12;
                const unsigned short* src;
                if (SRC == 3) {
                    src = &Ab[(size_t)(gm0 + row) * 192 + kb + c16 * 8];
                } else {
                    int g = gm0 + row;
                    int bt = g / 320, tok = g - bt * 320; bt += c0;
                    src = (tok < 64)
                        ? &Ab2[(size_t)(bt * 64 + tok) * 192 + kb + c16 * 8]
                        : &Ab[(size_t)bt * 49152 + ((tok >> 6) - 1) * 12288
                              + (tok & 63) * 192 + kb + c16 * 8];
                }
                u16x8 v = *reinterpret_cast<const u16x8*>(src);
                int boff = (c16 * 16) ^ ((row & 3) << 4);
                *reinterpret_cast<u16x8*>(As + row * 192 + boff) = v;
            }
        }
        // ---- stage B: 96 oc-rows x 96 k, pure bf16 copy ----
        for (int f8 = tid; f8 < 1152; f8 += 256) {
            int row = f8 / 12;
            int c16 = f8 - row * 12;
            u16x8 v = *reinterpret_cast<const u16x8*>(
                &Wsel[(size_t)(wrow0 + row) * 192 + kb + c16 * 8]);
            int boff = (c16 * 16) ^ ((row & 3) << 4);
            *reinterpret_cast<u16x8*>(Bs + row * 192 + boff) = v;
        }
        __syncthreads();

#pragma unroll
        for (int ks = 0; ks < 3; ks++) {
            s16x8 af[4], bf[3];
#pragma unroll
            for (int i = 0; i < 4; i++) {
                int row = wm * 64 + i * 16 + lr;
                int off = (ks * 64 + lk * 16) ^ ((row & 3) << 4);
                af[i] = *reinterpret_cast<const s16x8*>(As + row * 192 + off);
            }
#pragma unroll
            for (int j = 0; j < 3; j++) {
                int row = wn * 48 + j * 16 + lr;
                int off = (ks * 64 + lk * 16) ^ ((row & 3) << 4);
                bf[j] = *reinterpret_cast<const s16x8*>(Bs + row * 192 + off);
            }
#pragma unroll
            for (int i = 0; i < 4; i++)
#pragma unroll
                for (int j = 0; j < 3; j++)
                    acc[i][j] = __builtin_amdgcn_mfma_f32_16x16x32_bf16(
                        af[i], bf[j], acc[i][j], 0, 0, 0);
        }
        __syncthreads();
    }

    if (OUTBF == 0) {
#pragma unroll
        for (int j = 0; j < 3; j++) {
            int bcol = gn0 + wn * 48 + j * 16 + lr;
            float bv = (EPI == 3 && bcol >= 192) ? b1[bcol - 192] : b0[bcol];
            float* dst = (float*)C0v;
            int oc = bcol;
            if ((EPI == 2 || EPI == 3) && bcol >= 192) { dst = (float*)C1v; oc = bcol - 192; }
#pragma unroll
            for (int i = 0; i < 4; i++) {
                int rbase = gm0 + wm * 64 + i * 16 + lk * 4;
#pragma unroll
                for (int r = 0; r < 4; r++) {
                    float v = acc[i][j][r] + bv;
                    if (EPI == 1) v = 0.5f * v * (1.f + erff(v * 0.70710678118654752440f));
                    dst[(size_t)(rbase + r) * 192 + oc] = v;
                }
            }
        }
    } else {
        // bf16 out: restage via As (128*96 u16 = 24 KB), then coalesced stores
        unsigned short* As16 = (unsigned short*)As;
#pragma unroll
        for (int j = 0; j < 3; j++) {
            int bcol = gn0 + wn * 48 + j * 16 + lr;
            float bv = (EPI == 3 && bcol >= 192) ? b1[bcol - 192] : b0[bcol];
#pragma unroll
            for (int i = 0; i < 4; i++)
#pragma unroll
                for (int r = 0; r < 4; r++) {
                    float v = acc[i][j][r] + bv;
                    if (EPI == 1) v = 0.5f * v * (1.f + erff(v * 0.70710678118654752440f));
                    As16[(wm * 64 + i * 16 + lk * 4 + r) * 96 + wn * 48 + j * 16 + lr] = f2bf(v);
                }
        }
        __syncthreads();
        unsigned short* dst = (unsigned short*)((((EPI == 2) || (EPI == 3)) && hiN) ? C1v : C0v);
        const int oc0 = ((((EPI == 2) || (EPI == 3)) && hiN) ? gn0 - 192 : gn0);
#pragma unroll
        for (int it = 0; it < 6; it++) {
            int f8 = tid + it * 256;
            int row = f8 / 12, c16 = f8 - row * 12;
            u16x8 v = *reinterpret_cast<const u16x8*>(&As16[row * 96 + c16 * 8]);
            size_t idx;
            if (hbs == 0) {
                idx = (size_t)(gm0 + row) * 192 + oc0 + c16 * 8;
            } else {
                int col = oc0 + c16 * 8;          // 8-chunk stays in one head
                idx = (size_t)(col >> 5) * (size_t)hbs
                    + (size_t)(gm0 + row) * 32 + (col & 31);
            }
            *reinterpret_cast<u16x8*>(&dst[idx]) = v;
        }
    }
}

// ---------------------------------------------------------------------------
// Fused window attention, t-MERGED (r15 proven): block = (bb, m), 512 blocks,
// 768 thr = 12 waves; K/V/mask/rpbT staged F32 once, t=0..3 looped inside.
// VGPR 84, zero spill. Epilogue adds pos before bf16 rounding.
// ---------------------------------------------------------------------------
__global__ __launch_bounds__(768, 1)
void winattn_kernel(const float* __restrict__ qbuf,
                    const unsigned short* __restrict__ kbuf,
                    const unsigned short* __restrict__ vbuf,
                    const float* __restrict__ mask,
                    const float* __restrict__ rpbt, const float* __restrict__ pos,
                    unsigned short* __restrict__ xp)
{
    __shared__ float klds[64 * 192];       // 48 KB
    __shared__ float vlds[64 * 192];       // 48 KB
    __shared__ float mlds[64 * 65];        // 16.25 KB
    __shared__ float rldsT[6 * 225];       // 5.3 KB  [h][ridx]
    __shared__ float exm[768];
    __shared__ float exl[768];
    __shared__ unsigned obuf[6 * 64 * 17]; // 25.5 KB
    const int tid = threadIdx.x;
    const int bid = blockIdx.x;            // bb*4 + m
    const int bb = bid >> 2;
    const int m = bid & 3;
    const int w = tid >> 6;
    const int h = w >> 1;
    const int lane = tid & 63;

    const int kvbase = (bb * 4 + m) * 12288;
#pragma unroll
    for (int it = 0; it < 2; it++) {
        int i8 = tid + it * 768;
        u16x8 kq = *reinterpret_cast<const u16x8*>(&kbuf[kvbase + i8 * 8]);
        u16x8 vq = *reinterpret_cast<const u16x8*>(&vbuf[kvbase + i8 * 8]);
        f32x4 k0, k1, v0, v1;
#pragma unroll
        for (int e = 0; e < 4; e++) {
            k0[e] = bf2f(kq[e]); k1[e] = bf2f(kq[e + 4]);
            v0[e] = bf2f(vq[e]); v1[e] = bf2f(vq[e + 4]);
        }
        *reinterpret_cast<f32x4*>(&klds[i8 * 8]) = k0;
        *reinterpret_cast<f32x4*>(&klds[i8 * 8 + 4]) = k1;
        *reinterpret_cast<f32x4*>(&vlds[i8 * 8]) = v0;
        *reinterpret_cast<f32x4*>(&vlds[i8 * 8 + 4]) = v1;
    }
    const int widx = bb & 63;
    for (int f = tid; f < 4096; f += 768)
        mlds[(f >> 6) * 65 + (f & 63)] = mask[widx * 4096 + f];
    for (int f = tid; f < 1350; f += 768) {
        int hh = f / 225, rr = f - hh * 225;
        rldsT[f] = rpbt[rr * 6 + hh];
    }
    __syncthreads();

    const float scale = 0.17677669529663688110f;  // 1/sqrt(32)
    const int ni = lane >> 3, nj = lane & 7;
    const int e0 = (w & 1) << 5;

    for (int t = 0; t < 4; t++) {
        float qreg[32];
        const int qbase = ((bb * 4 + t) * 64 + lane) * 192 + h * 32;
#pragma unroll
        for (int j = 0; j < 8; j++) {
            float4 v = *reinterpret_cast<const float4*>(&qbuf[qbase + j * 4]);
            qreg[4 * j] = v.x; qreg[4 * j + 1] = v.y;
            qreg[4 * j + 2] = v.z; qreg[4 * j + 3] = v.w;
        }
        float s[32];
#pragma unroll
        for (int ee = 0; ee < 32; ee++) {
            int e = e0 + ee;
            const float4* kr = reinterpret_cast<const float4*>(&klds[e * 192 + h * 32]);
            float d0 = 0, d1 = 0, d2 = 0, d3 = 0;
#pragma unroll
            for (int q8 = 0; q8 < 8; q8++) {
                float4 k4 = kr[q8];
                d0 += qreg[q8 * 4] * k4.x;
                d1 += qreg[q8 * 4 + 1] * k4.y;
                d2 += qreg[q8 * 4 + 2] * k4.z;
                d3 += qreg[q8 * 4 + 3] * k4.w;
            }
            int ridx = (ni - (e >> 3) + 7) * 15 + (nj - (e & 7) + 7);
            s[ee] = (d0 + d1 + d2 + d3) * scale + rldsT[h * 225 + ridx] + mlds[lane * 65 + e];
        }
        float mrun = s[0];
#pragma unroll
        for (int ee = 1; ee < 32; ee++) mrun = fmaxf(mrun, s[ee]);
        float lrun = 0.f;
#pragma unroll
        for (int ee = 0; ee < 32; ee++) { s[ee] = __expf(s[ee] - mrun); lrun += s[ee]; }

        float o[32];
#pragma unroll
        for (int d = 0; d < 32; d++) o[d] = 0.f;
#pragma unroll
        for (int ee = 0; ee < 32; ee++) {
            float p = s[ee];
            const float4* vr = reinterpret_cast<const float4*>(&vlds[(e0 + ee) * 192 + h * 32]);
#pragma unroll
            for (int d8 = 0; d8 < 8; d8++) {
                float4 v4 = vr[d8];
                o[d8 * 4] += p * v4.x; o[d8 * 4 + 1] += p * v4.y;
                o[d8 * 4 + 2] += p * v4.z; o[d8 * 4 + 3] += p * v4.w;
            }
        }

        __syncthreads();                   // B1: prior t's obuf/exl reads done
        exm[w * 64 + lane] = mrun;
        __syncthreads();                   // B2
        float mo = exm[(w ^ 1) * 64 + lane];
        float mt = fmaxf(mrun, mo);
        float fs = __expf(mrun - mt);
        if (w & 1) {
            unsigned* ob = &obuf[h * 1088 + lane * 17];
#pragma unroll
            for (int j = 0; j < 16; j++) {
                unsigned lo = f2bf(fs * o[2 * j]);
                unsigned hi = f2bf(fs * o[2 * j + 1]);
                ob[j] = lo | (hi << 16);
            }
            exl[w * 64 + lane] = fs * lrun;
        }
        __syncthreads();                   // B3
        if (!(w & 1)) {
            float lt = fs * lrun + exl[(w + 1) * 64 + lane];
            const float inv = 1.f / lt;
            const unsigned* ob = &obuf[h * 1088 + lane * 17];
            const int obase = bb * 196608 + m * 49152 + t * 12288 + h * 2048 + lane * 32;
#pragma unroll
            for (int j = 0; j < 8; j++) {
                unsigned p0 = ob[2 * j], p1 = ob[2 * j + 1];
                float4 pv = *reinterpret_cast<const float4*>(&pos[h * 2048 + lane * 32 + j * 4]);
                u16x4 v;
                v[0] = f2bf((fs * o[4 * j]     + bf2f((unsigned short)(p0 & 0xffff))) * inv + pv.x);
                v[1] = f2bf((fs * o[4 * j + 1] + bf2f((unsigned short)(p0 >> 16))) * inv + pv.y);
                v[2] = f2bf((fs * o[4 * j + 2] + bf2f((unsigned short)(p1 & 0xffff))) * inv + pv.z);
                v[3] = f2bf((fs * o[4 * j + 3] + bf2f((unsigned short)(p1 >> 16))) * inv + pv.w);
                *reinterpret_cast<u16x4*>(&xp[obase + j * 4]) = v;
            }
        }
    }
}

// ---------------------------------------------------------------------------
// Pooling attention r16: block = (h, btl), 320 thr = 5 waves; wave w handles
// key tiles {w, w+5} of 10 (32 keys). kk/vv are HEAD-BLOCKED [h][tok][32]
// (h-stride hbs) -> staging is one contiguous 2 KB u16x8 stream per tile.
// qreg reloaded per key-tile iteration (#pragma unroll 1): cross-phase live
// ~40 regs, no spill. Final merge parallelized across 4 waves (8 dims each).
// ---------------------------------------------------------------------------
__global__ __launch_bounds__(320)
void poolattn3_kernel(const unsigned short* __restrict__ kk,
                      const unsigned short* __restrict__ vv,
                      const float* __restrict__ qq,
                      unsigned short* __restrict__ opool, int c0, int hbs)
{
    __shared__ float ubuf[10560];
    __shared__ float scm[320], scl[320];
    const int tid = threadIdx.x;
    const int w = tid >> 6, lane = tid & 63;
    const int h = blockIdx.x, btl = blockIdx.y;
    const int bt = c0 + btl;
    float* Kf = ubuf + w * 2048;
    float* Vf = Kf + 1024;

    const float scale = 0.17677669529663688110f;
    float mrun = -3.0e38f, lrun = 0.f;
    float o[32];
#pragma unroll
    for (int d = 0; d < 32; d++) o[d] = 0.f;

    const size_t qbase = (size_t)(bt * 64 + lane) * 192 + h * 32;
    const size_t hb = (size_t)h * hbs;

#pragma unroll 1
    for (int it = 0; it < 2; it++) {
        const int tt = w + it * 5;
        const unsigned short* ks = kk + hb + ((size_t)btl * 320 + tt * 32) * 32;
        const unsigned short* vs = vv + hb + ((size_t)btl * 320 + tt * 32) * 32;
        // contiguous staging: 128 lanes-worth x 16 B = 2 KB per tile
#pragma unroll
        for (int ci = 0; ci < 2; ci++) {
            int i8 = lane + ci * 64;           // 0..127
            u16x8 kv8 = *reinterpret_cast<const u16x8*>(&ks[i8 * 8]);
            u16x8 vv8 = *reinterpret_cast<const u16x8*>(&vs[i8 * 8]);
            f32x4 lo, hi, vlo, vhi;
#pragma unroll
            for (int e = 0; e < 4; e++) {
                lo[e] = bf2f(kv8[e]);  hi[e] = bf2f(kv8[e + 4]);
                vlo[e] = bf2f(vv8[e]); vhi[e] = bf2f(vv8[e + 4]);
            }
            *reinterpret_cast<f32x4*>(Kf + i8 * 8) = lo;
            *reinterpret_cast<f32x4*>(Kf + i8 * 8 + 4) = hi;
            *reinterpret_cast<f32x4*>(Vf + i8 * 8) = vlo;
            *reinterpret_cast<f32x4*>(Vf + i8 * 8 + 4) = vhi;
        }
        // reload q each iteration (keeps it out of cross-phase liveness)
        float qreg[32];
#pragma unroll
        for (int j = 0; j < 8; j++) {
            float4 v = *reinterpret_cast<const float4*>(&qq[qbase + j * 4]);
            qreg[4 * j] = v.x; qreg[4 * j + 1] = v.y;
            qreg[4 * j + 2] = v.z; qreg[4 * j + 3] = v.w;
        }
        float s[32];
#pragma unroll
        for (int j = 0; j < 32; j++) {
            const float4* kr = reinterpret_cast<const float4*>(Kf + j * 32);
            float d0 = 0, d1 = 0, d2 = 0, d3 = 0;
#pragma unroll
            for (int q8 = 0; q8 < 8; q8++) {
                float4 k4 = kr[q8];
                d0 += qreg[q8 * 4] * k4.x;
                d1 += qreg[q8 * 4 + 1] * k4.y;
                d2 += qreg[q8 * 4 + 2] * k4.z;
                d3 += qreg[q8 * 4 + 3] * k4.w;
            }
            s[j] = (d0 + d1 + d2 + d3) * scale;
        }
        float mt = s[0];
#pragma unroll
        for (int j = 1; j < 32; j++) mt = fmaxf(mt, s[j]);
        float mnew = fmaxf(mrun, mt);
        float fct = __expf(mrun - mnew);
        lrun *= fct;
#pragma unroll
        for (int d = 0; d < 32; d++) o[d] *= fct;
#pragma unroll
        for (int j = 0; j < 32; j++) { float p = __expf(s[j] - mnew); lrun += p; s[j] = p; }
#pragma unroll
        for (int j = 0; j < 32; j++) {
            float p = s[j];
            const float4* vr = reinterpret_cast<const float4*>(Vf + j * 32);
#pragma unroll
            for (int d8 = 0; d8 < 8; d8++) {
                float4 v4 = vr[d8];
                o[d8 * 4] += p * v4.x; o[d8 * 4 + 1] += p * v4.y;
                o[d8 * 4 + 2] += p * v4.z; o[d8 * 4 + 3] += p * v4.w;
            }
        }
        mrun = mnew;
    }
    __syncthreads();                 // everyone done with K/V region
    scm[w * 64 + lane] = mrun;
    scl[w * 64 + lane] = lrun;
#pragma unroll
    for (int d = 0; d < 32; d++) ubuf[w * 2112 + lane * 33 + d] = o[d];
    __syncthreads();

    if (tid < 256) {                 // 4-wave merge: q = tid&63, 8 dims each
        const int q = tid & 63, grp = tid >> 6;
        float m5 = scm[q];
#pragma unroll
        for (int ww = 1; ww < 5; ww++) m5 = fmaxf(m5, scm[ww * 64 + q]);
        float den = 0.f;
        float od[8];
#pragma unroll
        for (int e = 0; e < 8; e++) od[e] = 0.f;
#pragma unroll
        for (int ww = 0; ww < 5; ww++) {
            float f = __expf(scm[ww * 64 + q] - m5);
            den += f * scl[ww * 64 + q];
            const float* src = ubuf + ww * 2112 + q * 33 + grp * 8;
#pragma unroll
            for (int e = 0; e < 8; e++) od[e] += f * src[e];
        }
        const float inv = 1.f / den;
        const size_t ob = (size_t)(bt * 64 + q) * 192 + h * 32 + grp * 8;
        u16x4 v0, v1;
#pragma unroll
        for (int e = 0; e < 4; e++) { v0[e] = f2bf(od[e] * inv); v1[e] = f2bf(od[e + 4] * inv); }
        *reinterpret_cast<u16x4*>(&opool[ob]) = v0;
        *reinterpret_cast<u16x4*>(&opool[ob + 4]) = v1;
    }
}

extern "C" void kernel_launch(void* const* d_in, const int* in_sizes, int n_in,
                              void* d_out, int out_size, void* d_ws, size_t ws_size,
                              hipStream_t stream) {
    (void)in_sizes; (void)n_in; (void)out_size; (void)ws_size;
    const float* x      = (const float*)d_in[0];
    const float* x_kv   = (const float*)d_in[1];
    const float* mask   = (const float*)d_in[2];
    const float* rpbt   = (const float*)d_in[3];
    const float* q_w    = (const float*)d_in[4];
    const float* q_b    = (const float*)d_in[5];
    const float* kv_w   = (const float*)d_in[6];
    const float* kv_b   = (const float*)d_in[7];
    const float* pos    = (const float*)d_in[8];
    const float* pq_w   = (const float*)d_in[9];
    const float* pq_b   = (const float*)d_in[10];
    const float* pk_w   = (const float*)d_in[11];
    const float* pk_b   = (const float*)d_in[12];
    const float* pv_w   = (const float*)d_in[13];
    const float* pv_b   = (const float*)d_in[14];
    const float* po_w   = (const float*)d_in[15];
    const float* po_b   = (const float*)d_in[16];
    const float* proj_w = (const float*)d_in[17];
    const float* proj_b = (const float*)d_in[18];
    float* out = (float*)d_out;
    char* ws = (char*)d_ws;

    float*          qbuf   = (float*)(ws);                        // 24 MB
    unsigned short* xp     = (unsigned short*)(ws + 25165824u);   // 48 MB
    unsigned short* kbuf   = (unsigned short*)(ws + 75497472u);   // 12 MB
    unsigned short* vbuf   = (unsigned short*)(ws + 88080384u);   // 12 MB
    unsigned short* kkc    = (unsigned short*)(ws + 75497472u);   // 30 MB/chunk
    unsigned short* vvc    = (unsigned short*)(ws + 106954752u);  // 30 MB/chunk
    unsigned short* t0b    = (unsigned short*)(ws + 138412032u);  // 12.6 MB
    unsigned short* opoolb = (unsigned short*)(ws + 150994944u);  // 12.6 MB
    unsigned short* opob   = (unsigned short*)(ws + 163577856u);  // 12.6 MB
    unsigned short* wbf    = (unsigned short*)(ws + 176160768u);  // 0.59 MB
    float*          qq     = qbuf;
    const int HBS = 256 * 320 * 32;   // head-block stride (elements) per chunk

    dim3 blk(256);
    wcvt_kernel<<<1152, blk, 0, stream>>>(q_w, kv_w, pq_w, pk_w, pv_w, po_w, proj_w, wbf);
    // q = x @ q_w^T + q_b  (f32 A path)
    mgemm_kernel<0, 0, 0><<<dim3(256, 2), blk, 0, stream>>>(
        x, nullptr, nullptr, wbf, nullptr, q_b, nullptr, qbuf, nullptr, 0, 0);
    // k,v = x_kv @ kv_w^T + kv_b  (split, bf16 out, row-major)
    mgemm_kernel<0, 2, 1><<<dim3(256, 4), blk, 0, stream>>>(
        x_kv, nullptr, nullptr, wbf + 36864, nullptr, kv_b, nullptr, kbuf, vbuf, 0, 0);
    // window attention, t-merged; writes xp2 = attn_out + pos
    winattn_kernel<<<512, 768, 0, stream>>>(qbuf, kbuf, vbuf, mask, rpbt, pos, xp);
    // t0 = mean_m(xp2)
    prep_kernel<<<3072, blk, 0, stream>>>(xp, t0b);
    // qq = t0 @ pq_w^T + pq_b
    mgemm_kernel<3, 0, 0><<<dim3(256, 2), blk, 0, stream>>>(
        nullptr, t0b, nullptr, wbf + 110592, nullptr, pq_b, nullptr, qq, nullptr, 0, 0);
    // pooling in 2 chunks of 256 bt (kk/vv head-blocked)
    for (int c0 = 0; c0 < 512; c0 += 256) {
        mgemm_kernel<4, 3, 1><<<dim3(640, 4), blk, 0, stream>>>(
            nullptr, xp, t0b, wbf + 147456, wbf + 184320, pk_b, pv_b, kkc, vvc, c0, HBS);
        poolattn3_kernel<<<dim3(6, 256), 320, 0, stream>>>(kkc, vvc, qq, opoolb, c0, HBS);
    }
    // opo = gelu(opool @ po_w^T + po_b)  (bf16 in/out)
    mgemm_kernel<3, 1, 1><<<dim3(256, 2), blk, 0, stream>>>(
        nullptr, opoolb, nullptr, wbf + 221184, nullptr, po_b, nullptr, opob, nullptr, 0, 0);
    // out = opo @ proj_w^T + proj_b  (f32 out)
    mgemm_kernel<3, 0, 0><<<dim3(256, 2), blk, 0, stream>>>(
        nullptr, opob, nullptr, wbf + 258048, nullptr, proj_b, nullptr, out, nullptr, 0, 0);
}